// Round 1
// baseline (924.679 us; speedup 1.0000x reference)
//
#include <hip/hip_runtime.h>

#define BB 16
#define LL 4096
#define DD 64

typedef const float* __restrict__ cfp;
typedef float* __restrict__ fp;

__device__ __forceinline__ float4 ld4(const float* p){ return *reinterpret_cast<const float4*>(p); }
__device__ __forceinline__ void st4(float* p, float4 v){ *reinterpret_cast<float4*>(p) = v; }

// Load a 64x64 fp32 tile (row-major, ld=64) into LDS padded [64][68]
__device__ __forceinline__ void load_tile64(const float* __restrict__ g, float (*S)[68], int t){
  #pragma unroll
  for (int it = 0; it < 4; ++it) {
    int idx = it*256 + t;
    int r = idx >> 4, c4 = (idx & 15) << 2;
    st4(&S[r][c4], ld4(g + (size_t)r*64 + c4));
  }
}

// 64x64x64 tile GEMM: thread (m=t&15 -> d0=4m, rb=t>>4 -> r0=4rb) owns 4x4 block
__device__ __forceinline__ void mm64(const float (*Xs)[68], const float (*Ws)[68],
                                     int r0, int d0, float acc[4][4]){
  for (int c = 0; c < 64; ++c) {
    float4 w = ld4(&Ws[c][d0]);
    #pragma unroll
    for (int i = 0; i < 4; ++i) {
      float xv = Xs[r0+i][c];
      acc[i][0] = fmaf(xv, w.x, acc[i][0]);
      acc[i][1] = fmaf(xv, w.y, acc[i][1]);
      acc[i][2] = fmaf(xv, w.z, acc[i][2]);
      acc[i][3] = fmaf(xv, w.w, acc[i][3]);
    }
  }
}

// Row LayerNorm over 64 cols using partial sums, then scale/shift and write.
__device__ __forceinline__ void row_ln_write(float comb[4][4], int r0, int m, int t,
    float (*psum)[17], float (*pssq)[17], float* mu, float* rs,
    cfp g, cfp be, fp Y, size_t n0, int d0) {
  #pragma unroll
  for (int i = 0; i < 4; ++i) {
    float s = comb[i][0]+comb[i][1]+comb[i][2]+comb[i][3];
    float q = comb[i][0]*comb[i][0]+comb[i][1]*comb[i][1]
            + comb[i][2]*comb[i][2]+comb[i][3]*comb[i][3];
    psum[r0+i][m] = s; pssq[r0+i][m] = q;
  }
  __syncthreads();
  if (t < 64) {
    float s = 0.f, q = 0.f;
    #pragma unroll
    for (int k = 0; k < 16; ++k){ s += psum[t][k]; q += pssq[t][k]; }
    float mmu = s * 0.015625f;
    mu[t] = mmu;
    rs[t] = rsqrtf(q * 0.015625f - mmu*mmu + 1e-5f);
  }
  __syncthreads();
  float4 gv = ld4(g + d0), bv = ld4(be + d0);
  #pragma unroll
  for (int i = 0; i < 4; ++i) {
    int r = r0 + i;
    float mmu = mu[r], rr = rs[r];
    float4 o;
    o.x = (comb[i][0]-mmu)*rr*gv.x + bv.x;
    o.y = (comb[i][1]-mmu)*rr*gv.y + bv.y;
    o.z = (comb[i][2]-mmu)*rr*gv.z + bv.z;
    o.w = (comb[i][3]-mmu)*rr*gv.w + bv.w;
    st4(Y + (n0 + r)*64 + d0, o);
  }
}

// ---------------- pooling (mean over L) ----------------
__global__ __launch_bounds__(256) void k_pool_part(cfp h, fp pp) {
  int b = blockIdx.x, gblk = blockIdx.y, t = threadIdx.x;
  int c = t & 63, r = t >> 6;
  const float* base = h + ((size_t)b*LL + (size_t)gblk*256)*64;
  float acc = 0.f;
  for (int l = r; l < 256; l += 4) acc += base[(size_t)l*64 + c];
  __shared__ float red[4][64];
  red[r][c] = acc; __syncthreads();
  if (t < 64) pp[(b*16 + gblk)*64 + t] = red[0][t]+red[1][t]+red[2][t]+red[3][t];
}

__global__ void k_pool_fin(cfp pp, fp means) {
  int b = blockIdx.x, c = threadIdx.x;
  float s = 0.f;
  for (int g = 0; g < 16; ++g) s += pp[(b*16+g)*64 + c];
  means[b*64 + c] = s * (1.f/LL);
}

// ---------------- dynamic conv: attention + effective kernel ----------------
__global__ __launch_bounds__(256) void k_weff(cfp means, cfp w1, cfp b1, cfp w2, cfp b2,
                                              cfp kern, fp weff) {
  int b = blockIdx.x, t = threadIdx.x;
  __shared__ float pooled[64], hdn[16], attn[3];
  if (t < 64) pooled[t] = means[b*64 + t];
  __syncthreads();
  if (t < 16) {
    float a = b1[t];
    for (int c = 0; c < 64; ++c) a += pooled[c]*w1[t*64 + c];
    hdn[t] = fmaxf(a, 0.f);
  }
  __syncthreads();
  if (t < 3) {
    float a = b2[t];
    for (int j = 0; j < 16; ++j) a += hdn[j]*w2[t*16 + j];
    attn[t] = a;
  }
  __syncthreads();
  if (t == 0) {
    float m = fmaxf(attn[0], fmaxf(attn[1], attn[2]));
    float e0 = __expf(attn[0]-m), e1 = __expf(attn[1]-m), e2 = __expf(attn[2]-m);
    float s = e0+e1+e2;
    attn[0]=e0/s; attn[1]=e1/s; attn[2]=e2/s;
  }
  __syncthreads();
  float a0=attn[0], a1=attn[1], a2=attn[2];
  for (int e = t; e < 12288; e += 256) {
    int co = e & 63, ci = (e>>6) & 63, kh = e >> 12;
    size_t base = ((size_t)co*64 + ci)*9 + kh*3 + 1;   // kw=1 only (W=1 with pad)
    float v = a0*kern[base] + a1*kern[base + 36864] + a2*kern[base + 2*36864];
    weff[(size_t)b*12288 + ((size_t)(kh*64 + ci)*64 + co)] = v;
  }
}

// ---------------- 3-tap conv along L as 192-deep GEMM ----------------
__global__ __launch_bounds__(256) void k_conv(cfp hin, cfp weff, fp hout) {
  int b = blockIdx.x, wblk = blockIdx.y, t = threadIdx.x;
  int n0 = wblk*64;
  __shared__ float Ws[192][68];   // [kh*64+ci][co]
  __shared__ float Ts[66][68];    // rows n0-1 .. n0+64
  const float* wsrc = weff + (size_t)b*12288;
  for (int idx = t; idx < 3072; idx += 256) {
    float4 v = ld4(wsrc + (size_t)idx*4);
    int e = idx*4; int co = e & 63; int rcw = e >> 6;
    st4(&Ws[rcw][co], v);
  }
  for (int idx = t; idx < 1056; idx += 256) {
    int r = idx >> 4, c4 = (idx & 15)*4;
    int gr = n0 - 1 + r;
    float4 v = make_float4(0.f,0.f,0.f,0.f);
    if (gr >= 0 && gr < LL) v = ld4(hin + ((size_t)b*LL + gr)*64 + c4);
    st4(&Ts[r][c4], v);
  }
  __syncthreads();
  int m = t & 15, rb = t >> 4;
  int co0 = m*4, r0 = rb*4;
  float acc[4][4] = {};
  for (int cc = 0; cc < 192; ++cc) {
    int kh = cc >> 6, ci = cc & 63;
    float4 w = ld4(&Ws[cc][co0]);
    #pragma unroll
    for (int i = 0; i < 4; ++i) {
      float xv = Ts[r0 + i + kh][ci];
      acc[i][0] = fmaf(xv, w.x, acc[i][0]);
      acc[i][1] = fmaf(xv, w.y, acc[i][1]);
      acc[i][2] = fmaf(xv, w.z, acc[i][2]);
      acc[i][3] = fmaf(xv, w.w, acc[i][3]);
    }
  }
  #pragma unroll
  for (int i = 0; i < 4; ++i)
    st4(hout + ((size_t)b*LL + n0 + r0 + i)*64 + co0,
        make_float4(acc[i][0],acc[i][1],acc[i][2],acc[i][3]));
}

// ---------------- generic 64->64 GEMM + bias ----------------
__global__ __launch_bounds__(256) void k_gemm64_bias(cfp X, cfp W, cfp bias, fp Y) {
  __shared__ float Xs[64][68], Ws[64][68];
  int t = threadIdx.x; size_t n0 = (size_t)blockIdx.x*64;
  load_tile64(X + n0*64, Xs, t);
  load_tile64(W, Ws, t);
  __syncthreads();
  int m = t&15, rb = t>>4, d0 = m*4, r0 = rb*4;
  float acc[4][4] = {};
  mm64(Xs, Ws, r0, d0, acc);
  float4 bv = ld4(bias + d0);
  #pragma unroll
  for (int i = 0; i < 4; ++i)
    st4(Y + (n0 + r0 + i)*64 + d0,
        make_float4(acc[i][0]+bv.x, acc[i][1]+bv.y, acc[i][2]+bv.z, acc[i][3]+bv.w));
}

// ---------------- fused q,k,v GEMMs (X tile loaded once) ----------------
__global__ __launch_bounds__(256) void k_qkv(cfp X,
    cfp Wq, cfp bq, fp Yq, cfp Wk, cfp bk, fp Yk, cfp Wv, cfp bv, fp Yv) {
  __shared__ float Xs[64][68], Ws[64][68];
  int t = threadIdx.x; size_t n0 = (size_t)blockIdx.x*64;
  load_tile64(X + n0*64, Xs, t);
  const float* Wp[3] = {Wq, Wk, Wv};
  const float* bp[3] = {bq, bk, bv};
  float* Yp[3] = {Yq, Yk, Yv};
  int m = t&15, rb = t>>4, d0 = m*4, r0 = rb*4;
  for (int kk = 0; kk < 3; ++kk) {
    load_tile64(Wp[kk], Ws, t);
    __syncthreads();
    float acc[4][4] = {};
    mm64(Xs, Ws, r0, d0, acc);
    float4 b4 = ld4(bp[kk] + d0);
    #pragma unroll
    for (int i = 0; i < 4; ++i)
      st4(Yp[kk] + (n0 + r0 + i)*64 + d0,
          make_float4(acc[i][0]+b4.x, acc[i][1]+b4.y, acc[i][2]+b4.z, acc[i][3]+b4.w));
    __syncthreads();
  }
}

// ---------------- agent attention: softmax over L, weighted V sum ----------------
__global__ __launch_bounds__(256) void k_agent(cfp h, cfp v, cfp anb, cfp means, fp agv) {
  int b = blockIdx.x, hh = blockIdx.y, t = threadIdx.x;
  __shared__ float sv[4096];
  __shared__ float red[256];
  __shared__ float redw[4][8];
  float ag[8];
  #pragma unroll
  for (int d = 0; d < 8; ++d) ag[d] = means[b*64 + hh*8 + d];
  const float scale = 0.35355339059327373f;  // 8^-0.5
  const float* hb = h + (size_t)b*LL*64 + hh*8;
  const float* anbb = anb + (size_t)hh*4096;
  float lm = -1e30f;
  for (int n = t; n < 4096; n += 256) {
    const float* hp = hb + (size_t)n*64;
    float4 a = ld4(hp), c = ld4(hp+4);
    float sc = ag[0]*a.x+ag[1]*a.y+ag[2]*a.z+ag[3]*a.w
             + ag[4]*c.x+ag[5]*c.y+ag[6]*c.z+ag[7]*c.w;
    sc = sc*scale + anbb[n];
    sv[n] = sc; lm = fmaxf(lm, sc);
  }
  red[t] = lm; __syncthreads();
  for (int off = 128; off > 0; off >>= 1) { if (t < off) red[t] = fmaxf(red[t], red[t+off]); __syncthreads(); }
  float M = red[0]; __syncthreads();
  float lsum = 0.f;
  for (int n = t; n < 4096; n += 256) { float p = __expf(sv[n]-M); sv[n] = p; lsum += p; }
  red[t] = lsum; __syncthreads();
  for (int off = 128; off > 0; off >>= 1) { if (t < off) red[t] += red[t+off]; __syncthreads(); }
  float rS = 1.f / red[0];
  float va[8] = {};
  const float* vb = v + (size_t)b*LL*64 + hh*8;
  for (int n = t; n < 4096; n += 256) {
    float p = sv[n];
    const float* vp = vb + (size_t)n*64;
    float4 a = ld4(vp), c = ld4(vp+4);
    va[0]+=p*a.x; va[1]+=p*a.y; va[2]+=p*a.z; va[3]+=p*a.w;
    va[4]+=p*c.x; va[5]+=p*c.y; va[6]+=p*c.z; va[7]+=p*c.w;
  }
  #pragma unroll
  for (int d = 0; d < 8; ++d) {
    float xx = va[d];
    #pragma unroll
    for (int off = 32; off > 0; off >>= 1) xx += __shfl_down(xx, off);
    if ((t & 63) == 0) redw[t >> 6][d] = xx;
  }
  __syncthreads();
  if (t < 8) agv[(b*8 + hh)*8 + t] = (redw[0][t]+redw[1][t]+redw[2][t]+redw[3][t]) * rS;
}

// ---------------- windowed local attention (4 heads, WIN=64, dk=16) ----------------
__global__ __launch_bounds__(256) void k_winattn(cfp Q, cfp K, cfp V, fp O) {
  __shared__ float Qs[64][68], Ks[64][68], Vs[64][68], Os[64][68];
  __shared__ float Opart[4][64][16];
  __shared__ float pmax[4][64], psm[4][64];
  int t = threadIdx.x; size_t n0 = (size_t)blockIdx.x*64;
  load_tile64(Q + n0*64, Qs, t);
  load_tile64(K + n0*64, Ks, t);
  load_tile64(V + n0*64, Vs, t);
  __syncthreads();
  int i = t & 63, g = t >> 6;
  for (int hh = 0; hh < 4; ++hh) {
    int hc = hh*16;
    float qf[16];
    #pragma unroll
    for (int k4 = 0; k4 < 4; ++k4) {
      float4 qv = ld4(&Qs[i][hc + k4*4]);
      qf[k4*4]=qv.x; qf[k4*4+1]=qv.y; qf[k4*4+2]=qv.z; qf[k4*4+3]=qv.w;
    }
    float s[16]; float lm = -1e30f;
    #pragma unroll
    for (int jj = 0; jj < 16; ++jj) {
      int j = g*16 + jj;
      float acc = 0.f;
      #pragma unroll
      for (int k4 = 0; k4 < 4; ++k4) {
        float4 kv = ld4(&Ks[j][hc + k4*4]);
        acc += qf[k4*4]*kv.x + qf[k4*4+1]*kv.y + qf[k4*4+2]*kv.z + qf[k4*4+3]*kv.w;
      }
      s[jj] = acc * 0.25f;
      lm = fmaxf(lm, s[jj]);
    }
    pmax[g][i] = lm;
    __syncthreads();
    float M = fmaxf(fmaxf(pmax[0][i], pmax[1][i]), fmaxf(pmax[2][i], pmax[3][i]));
    float p[16]; float ls = 0.f;
    #pragma unroll
    for (int jj = 0; jj < 16; ++jj) { p[jj] = __expf(s[jj]-M); ls += p[jj]; }
    psm[g][i] = ls;
    float oa[16] = {};
    #pragma unroll
    for (int jj = 0; jj < 16; ++jj) {
      int j = g*16 + jj;
      #pragma unroll
      for (int k4 = 0; k4 < 4; ++k4) {
        float4 vv = ld4(&Vs[j][hc + k4*4]);
        oa[k4*4]   = fmaf(p[jj], vv.x, oa[k4*4]);
        oa[k4*4+1] = fmaf(p[jj], vv.y, oa[k4*4+1]);
        oa[k4*4+2] = fmaf(p[jj], vv.z, oa[k4*4+2]);
        oa[k4*4+3] = fmaf(p[jj], vv.w, oa[k4*4+3]);
      }
    }
    #pragma unroll
    for (int k4 = 0; k4 < 4; ++k4)
      st4(&Opart[g][i][k4*4], make_float4(oa[k4*4],oa[k4*4+1],oa[k4*4+2],oa[k4*4+3]));
    __syncthreads();
    #pragma unroll
    for (int q = 0; q < 4; ++q) {
      int flat = q*256 + t;
      int ii = flat >> 4, d = flat & 15;
      float den = psm[0][ii]+psm[1][ii]+psm[2][ii]+psm[3][ii];
      Os[ii][hc + d] = (Opart[0][ii][d]+Opart[1][ii][d]+Opart[2][ii][d]+Opart[3][ii][d]) / den;
    }
    __syncthreads();
  }
  #pragma unroll
  for (int it = 0; it < 4; ++it) {
    int idx = it*256 + t; int r = idx >> 4, c4 = (idx & 15)*4;
    st4(O + (n0 + r)*64 + c4, ld4(&Os[r][c4]));
  }
}

// ---------------- o@wo + bo + residual(h) + agent broadcast + lepe(v) -> LN1 ----------------
__global__ __launch_bounds__(256) void k_wo_ln1(cfp O, cfp W, cfp bo, cfp h, cfp vg, cfp agv,
                                                cfp g1, cfp be1, fp h1) {
  __shared__ float Xs[64][68], Ws[64][68];
  __shared__ float psum[64][17], pssq[64][17];
  __shared__ float mu[64], rs[64];
  int t = threadIdx.x; size_t n0 = (size_t)blockIdx.x*64;
  int b = (int)(n0 >> 12);
  load_tile64(O + n0*64, Xs, t);
  load_tile64(W, Ws, t);
  __syncthreads();
  int m = t&15, rb = t>>4, d0 = m*4, r0 = rb*4;
  float acc[4][4] = {};
  mm64(Xs, Ws, r0, d0, acc);
  float4 bv = ld4(bo + d0);
  float4 av = ld4(agv + b*64 + d0);
  float comb[4][4];
  #pragma unroll
  for (int i = 0; i < 4; ++i) {
    size_t row = n0 + r0 + i;
    float4 hv = ld4(h + row*64 + d0);
    float4 vv = ld4(vg + row*64 + d0);
    comb[i][0] = acc[i][0]+bv.x+av.x+hv.x+vv.x;
    comb[i][1] = acc[i][1]+bv.y+av.y+hv.y+vv.y;
    comb[i][2] = acc[i][2]+bv.z+av.z+hv.z+vv.z;
    comb[i][3] = acc[i][3]+bv.w+av.w+hv.w+vv.w;
  }
  row_ln_write(comb, r0, m, t, psum, pssq, mu, rs, g1, be1, h1, n0, d0);
}

// ---------------- FFN (64->128 relu ->64) + residual + LN2, fully fused ----------------
__global__ __launch_bounds__(256) void k_ffn_ln(cfp X, cfp W1, cfp b1, cfp W2, cfp b2,
                                                cfp g2, cfp be2, fp Y) {
  __shared__ float Xs[64][68];
  __shared__ float Wsh[8704];        // W1 as [64][132], later W2 as [128][68]
  __shared__ float Hid[64][132];
  __shared__ float psum[64][17], pssq[64][17];
  __shared__ float mu[64], rs[64];
  int t = threadIdx.x; size_t n0 = (size_t)blockIdx.x*64;
  load_tile64(X + n0*64, Xs, t);
  for (int idx = t; idx < 2048; idx += 256) {
    int c = idx >> 5, f4 = (idx & 31)*4;
    st4(&Wsh[c*132 + f4], ld4(W1 + c*128 + f4));
  }
  __syncthreads();
  int m = t&15, rb = t>>4, r0 = rb*4;
  {
    int f0 = m*8;
    float acc[4][8] = {};
    for (int c = 0; c < 64; ++c) {
      float4 wa = ld4(&Wsh[c*132 + f0]);
      float4 wb = ld4(&Wsh[c*132 + f0 + 4]);
      #pragma unroll
      for (int i = 0; i < 4; ++i) {
        float xv = Xs[r0+i][c];
        acc[i][0]=fmaf(xv,wa.x,acc[i][0]); acc[i][1]=fmaf(xv,wa.y,acc[i][1]);
        acc[i][2]=fmaf(xv,wa.z,acc[i][2]); acc[i][3]=fmaf(xv,wa.w,acc[i][3]);
        acc[i][4]=fmaf(xv,wb.x,acc[i][4]); acc[i][5]=fmaf(xv,wb.y,acc[i][5]);
        acc[i][6]=fmaf(xv,wb.z,acc[i][6]); acc[i][7]=fmaf(xv,wb.w,acc[i][7]);
      }
    }
    float4 ba = ld4(b1 + f0), bb = ld4(b1 + f0 + 4);
    #pragma unroll
    for (int i = 0; i < 4; ++i) {
      st4(&Hid[r0+i][f0],   make_float4(fmaxf(acc[i][0]+ba.x,0.f), fmaxf(acc[i][1]+ba.y,0.f),
                                        fmaxf(acc[i][2]+ba.z,0.f), fmaxf(acc[i][3]+ba.w,0.f)));
      st4(&Hid[r0+i][f0+4], make_float4(fmaxf(acc[i][4]+bb.x,0.f), fmaxf(acc[i][5]+bb.y,0.f),
                                        fmaxf(acc[i][6]+bb.z,0.f), fmaxf(acc[i][7]+bb.w,0.f)));
    }
  }
  __syncthreads();
  for (int idx = t; idx < 2048; idx += 256) {
    int f = idx >> 4, d4 = (idx & 15)*4;
    st4(&Wsh[f*68 + d4], ld4(W2 + f*64 + d4));
  }
  __syncthreads();
  int d0 = m*4;
  float acc[4][4] = {};
  for (int f = 0; f < 128; ++f) {
    float4 w = ld4(&Wsh[f*68 + d0]);
    #pragma unroll
    for (int i = 0; i < 4; ++i) {
      float xv = Hid[r0+i][f];
      acc[i][0]=fmaf(xv,w.x,acc[i][0]); acc[i][1]=fmaf(xv,w.y,acc[i][1]);
      acc[i][2]=fmaf(xv,w.z,acc[i][2]); acc[i][3]=fmaf(xv,w.w,acc[i][3]);
    }
  }
  float4 bv = ld4(b2 + d0);
  float comb[4][4];
  #pragma unroll
  for (int i = 0; i < 4; ++i) {
    comb[i][0] = acc[i][0]+bv.x+Xs[r0+i][d0+0];
    comb[i][1] = acc[i][1]+bv.y+Xs[r0+i][d0+1];
    comb[i][2] = acc[i][2]+bv.z+Xs[r0+i][d0+2];
    comb[i][3] = acc[i][3]+bv.w+Xs[r0+i][d0+3];
  }
  row_ln_write(comb, r0, m, t, psum, pssq, mu, rs, g2, be2, Y, n0, d0);
}

extern "C" void kernel_launch(void* const* d_in, const int* in_sizes, int n_in,
                              void* d_out, int out_size, void* d_ws, size_t ws_size,
                              hipStream_t stream) {
  (void)in_sizes; (void)n_in; (void)out_size; (void)ws_size;
  const float* x    = (const float*)d_in[0];
  const float* dck  = (const float*)d_in[1];
  const float* dcw1 = (const float*)d_in[2];
  const float* dcb1 = (const float*)d_in[3];
  const float* dcw2 = (const float*)d_in[4];
  const float* dcb2 = (const float*)d_in[5];
  const float* embw = (const float*)d_in[6];
  const float* embb = (const float*)d_in[7];
  const float* getvw= (const float*)d_in[8];
  const float* getvb= (const float*)d_in[9];
  const float* anb  = (const float*)d_in[10];
  // d_in[11] = na_bias: provably unused (softmax over size-1 axis == 1)
  const float* wq = (const float*)d_in[12]; const float* bq = (const float*)d_in[13];
  const float* wk = (const float*)d_in[14]; const float* bk = (const float*)d_in[15];
  const float* wv = (const float*)d_in[16]; const float* bv = (const float*)d_in[17];
  const float* wo = (const float*)d_in[18]; const float* bo = (const float*)d_in[19];
  const float* fw1= (const float*)d_in[20]; const float* fb1= (const float*)d_in[21];
  const float* fw2= (const float*)d_in[22]; const float* fb2= (const float*)d_in[23];
  const float* g1 = (const float*)d_in[24]; const float* be1= (const float*)d_in[25];
  const float* g2 = (const float*)d_in[26]; const float* be2= (const float*)d_in[27];

  float* out = (float*)d_out;
  float* ws  = (float*)d_ws;
  const size_t SZ = (size_t)BB*LL*DD;   // 4,194,304 floats
  float* bufA = ws;
  float* bufB = ws + SZ;
  float* vbuf = ws + 2*SZ;
  float* qb   = ws + 3*SZ;   // also reused as h1 buffer
  float* kb   = ws + 4*SZ;
  float* vl   = ws + 5*SZ;
  float* pp    = ws + 6*SZ;
  float* means = pp + BB*16*64;
  float* agv   = means + BB*64;
  float* wef   = agv + BB*64;
  // total: 6*SZ + 215,040 floats ~= 101.5 MB of workspace

  dim3 blk(256);
  const int NT = BB*LL/64;  // 1024 row-tiles

  // ---- dynamic conv stem (3 stages) ----
  const float* cin = x;
  float* cout = bufA;
  for (int i = 0; i < 3; ++i) {
    k_pool_part<<<dim3(BB,16), blk, 0, stream>>>(cin, pp);
    k_pool_fin<<<BB, 64, 0, stream>>>(pp, means);
    k_weff<<<BB, blk, 0, stream>>>(means, dcw1 + i*16*64, dcb1 + i*16,
                                   dcw2 + i*3*16, dcb2 + i*3,
                                   dck + (size_t)i*3*64*64*9, wef);
    k_conv<<<dim3(BB,64), blk, 0, stream>>>(cin, wef, cout);
    cin = cout;
    cout = (cout == bufA) ? bufB : bufA;
  }
  // cin == bufA after 3 stages; embed into bufB
  k_gemm64_bias<<<NT, blk, 0, stream>>>(cin, embw, embb, bufB);

  float* h  = bufB;
  float* hn = bufA;
  for (int i = 0; i < 3; ++i) {
    k_pool_part<<<dim3(BB,16), blk, 0, stream>>>(h, pp);
    k_pool_fin<<<BB, 64, 0, stream>>>(pp, means);
    k_gemm64_bias<<<NT, blk, 0, stream>>>(h, getvw + i*4096, getvb + i*64, vbuf);
    k_agent<<<dim3(BB,8), blk, 0, stream>>>(h, vbuf, anb + (size_t)i*8*4096, means, agv);
    k_qkv<<<NT, blk, 0, stream>>>(h, wq + i*4096, bq + i*64, qb,
                                     wk + i*4096, bk + i*64, kb,
                                     wv + i*4096, bv + i*64, vl);
    k_winattn<<<NT, blk, 0, stream>>>(qb, kb, vl, out);        // out doubles as o-buffer
    k_wo_ln1<<<NT, blk, 0, stream>>>(out, wo + i*4096, bo + i*64, h, vbuf, agv,
                                     g1 + i*64, be1 + i*64, qb); // qb doubles as h1
    float* dst = (i == 2) ? out : hn;
    k_ffn_ln<<<NT, blk, 0, stream>>>(qb, fw1 + (size_t)i*64*128, fb1 + i*128,
                                     fw2 + (size_t)i*128*64, fb2 + i*64,
                                     g2 + i*64, be2 + i*64, dst);
    float* tmp = h; h = hn; hn = tmp;
  }
}

// Round 2
// 720.884 us; speedup vs baseline: 1.2827x; 1.2827x over previous
//
#include <hip/hip_runtime.h>

#define BB 16
#define LL 4096
#define DD 64

typedef const float* __restrict__ cfp;
typedef float* __restrict__ fp;

__device__ __forceinline__ float4 ld4(const float* p){ return *reinterpret_cast<const float4*>(p); }
__device__ __forceinline__ void st4(float* p, float4 v){ *reinterpret_cast<float4*>(p) = v; }

// Load a 64x64 fp32 tile (row-major, ld=64) into LDS padded [64][68]
// ([68] stride = 272 B = 17*16 B, so every row stays 16B-aligned for float4 ops)
__device__ __forceinline__ void load_tile64(const float* __restrict__ g, float (*S)[68], int t){
  #pragma unroll
  for (int it = 0; it < 4; ++it) {
    int idx = it*256 + t;
    int r = idx >> 4, c4 = (idx & 15) << 2;
    st4(&S[r][c4], ld4(g + (size_t)r*64 + c4));
  }
}

// 64x64x64 tile GEMM: thread (m=t&15 -> d0=4m, rb=t>>4 -> r0=4rb) owns 4x4 block
__device__ __forceinline__ void mm64(const float (*Xs)[68], const float (*Ws)[68],
                                     int r0, int d0, float acc[4][4]){
  for (int c = 0; c < 64; ++c) {
    float4 w = ld4(&Ws[c][d0]);
    #pragma unroll
    for (int i = 0; i < 4; ++i) {
      float xv = Xs[r0+i][c];
      acc[i][0] = fmaf(xv, w.x, acc[i][0]);
      acc[i][1] = fmaf(xv, w.y, acc[i][1]);
      acc[i][2] = fmaf(xv, w.z, acc[i][2]);
      acc[i][3] = fmaf(xv, w.w, acc[i][3]);
    }
  }
}

// Row LayerNorm over 64 cols; writes normalized rows to GLOBAL Y.
__device__ __forceinline__ void row_ln_write(float comb[4][4], int r0, int m, int t,
    float (*psum)[17], float (*pssq)[17], float* mu, float* rs,
    cfp g, cfp be, fp Y, size_t n0, int d0) {
  #pragma unroll
  for (int i = 0; i < 4; ++i) {
    float s = comb[i][0]+comb[i][1]+comb[i][2]+comb[i][3];
    float q = comb[i][0]*comb[i][0]+comb[i][1]*comb[i][1]
            + comb[i][2]*comb[i][2]+comb[i][3]*comb[i][3];
    psum[r0+i][m] = s; pssq[r0+i][m] = q;
  }
  __syncthreads();
  if (t < 64) {
    float s = 0.f, q = 0.f;
    #pragma unroll
    for (int k = 0; k < 16; ++k){ s += psum[t][k]; q += pssq[t][k]; }
    float mmu = s * 0.015625f;
    mu[t] = mmu;
    rs[t] = rsqrtf(q * 0.015625f - mmu*mmu + 1e-5f);
  }
  __syncthreads();
  float4 gv = ld4(g + d0), bv = ld4(be + d0);
  #pragma unroll
  for (int i = 0; i < 4; ++i) {
    int r = r0 + i;
    float mmu = mu[r], rr = rs[r];
    float4 o;
    o.x = (comb[i][0]-mmu)*rr*gv.x + bv.x;
    o.y = (comb[i][1]-mmu)*rr*gv.y + bv.y;
    o.z = (comb[i][2]-mmu)*rr*gv.z + bv.z;
    o.w = (comb[i][3]-mmu)*rr*gv.w + bv.w;
    st4(Y + (n0 + r)*64 + d0, o);
  }
}

// Same LayerNorm but writes into an LDS [64][68] tile (for in-kernel chaining).
__device__ __forceinline__ void row_ln_lds(float comb[4][4], int r0, int m, int t,
    float (*psum)[17], float (*pssq)[17], float* mu, float* rs,
    cfp g, cfp be, float (*Hs)[68], int d0) {
  #pragma unroll
  for (int i = 0; i < 4; ++i) {
    float s = comb[i][0]+comb[i][1]+comb[i][2]+comb[i][3];
    float q = comb[i][0]*comb[i][0]+comb[i][1]*comb[i][1]
            + comb[i][2]*comb[i][2]+comb[i][3]*comb[i][3];
    psum[r0+i][m] = s; pssq[r0+i][m] = q;
  }
  __syncthreads();
  if (t < 64) {
    float s = 0.f, q = 0.f;
    #pragma unroll
    for (int k = 0; k < 16; ++k){ s += psum[t][k]; q += pssq[t][k]; }
    float mmu = s * 0.015625f;
    mu[t] = mmu;
    rs[t] = rsqrtf(q * 0.015625f - mmu*mmu + 1e-5f);
  }
  __syncthreads();
  float4 gv = ld4(g + d0), bv = ld4(be + d0);
  #pragma unroll
  for (int i = 0; i < 4; ++i) {
    int r = r0 + i;
    float mmu = mu[r], rr = rs[r];
    float4 o;
    o.x = (comb[i][0]-mmu)*rr*gv.x + bv.x;
    o.y = (comb[i][1]-mmu)*rr*gv.y + bv.y;
    o.z = (comb[i][2]-mmu)*rr*gv.z + bv.z;
    o.w = (comb[i][3]-mmu)*rr*gv.w + bv.w;
    st4(&Hs[r][d0], o);
  }
}

// ---------------- pooling (mean over L) ----------------
__global__ __launch_bounds__(256) void k_pool_part(cfp h, fp pp) {
  int b = blockIdx.x, gblk = blockIdx.y, t = threadIdx.x;
  int c = t & 63, r = t >> 6;
  const float* base = h + ((size_t)b*LL + (size_t)gblk*256)*64;
  float acc = 0.f;
  for (int l = r; l < 256; l += 4) acc += base[(size_t)l*64 + c];
  __shared__ float red[4][64];
  red[r][c] = acc; __syncthreads();
  if (t < 64) pp[(b*16 + gblk)*64 + t] = red[0][t]+red[1][t]+red[2][t]+red[3][t];
}

__global__ void k_pool_fin(cfp pp, fp means) {
  int b = blockIdx.x, c = threadIdx.x;
  float s = 0.f;
  for (int g = 0; g < 16; ++g) s += pp[(b*16+g)*64 + c];
  means[b*64 + c] = s * (1.f/LL);
}

// ---------------- dynamic conv: attention + effective kernel ----------------
__global__ __launch_bounds__(256) void k_weff(cfp means, cfp w1, cfp b1, cfp w2, cfp b2,
                                              cfp kern, fp weff) {
  int b = blockIdx.x, t = threadIdx.x;
  __shared__ float pooled[64], hdn[16], attn[3];
  if (t < 64) pooled[t] = means[b*64 + t];
  __syncthreads();
  if (t < 16) {
    float a = b1[t];
    for (int c = 0; c < 64; ++c) a += pooled[c]*w1[t*64 + c];
    hdn[t] = fmaxf(a, 0.f);
  }
  __syncthreads();
  if (t < 3) {
    float a = b2[t];
    for (int j = 0; j < 16; ++j) a += hdn[j]*w2[t*16 + j];
    attn[t] = a;
  }
  __syncthreads();
  if (t == 0) {
    float m = fmaxf(attn[0], fmaxf(attn[1], attn[2]));
    float e0 = __expf(attn[0]-m), e1 = __expf(attn[1]-m), e2 = __expf(attn[2]-m);
    float s = e0+e1+e2;
    attn[0]=e0/s; attn[1]=e1/s; attn[2]=e2/s;
  }
  __syncthreads();
  float a0=attn[0], a1=attn[1], a2=attn[2];
  for (int e = t; e < 12288; e += 256) {
    int co = e & 63, ci = (e>>6) & 63, kh = e >> 12;
    size_t base = ((size_t)co*64 + ci)*9 + kh*3 + 1;   // kw=1 only (W=1 with pad)
    float v = a0*kern[base] + a1*kern[base + 36864] + a2*kern[base + 2*36864];
    weff[(size_t)b*12288 + ((size_t)(kh*64 + ci)*64 + co)] = v;
  }
}

// ---------------- 3-tap conv along L as 192-deep GEMM ----------------
__global__ __launch_bounds__(256) void k_conv(cfp hin, cfp weff, fp hout) {
  int b = blockIdx.x, wblk = blockIdx.y, t = threadIdx.x;
  int n0 = wblk*64;
  __shared__ float Ws[192][68];   // [kh*64+ci][co]
  __shared__ float Ts[66][68];    // rows n0-1 .. n0+64
  const float* wsrc = weff + (size_t)b*12288;
  for (int idx = t; idx < 3072; idx += 256) {
    float4 v = ld4(wsrc + (size_t)idx*4);
    int e = idx*4; int co = e & 63; int rcw = e >> 6;
    st4(&Ws[rcw][co], v);
  }
  for (int idx = t; idx < 1056; idx += 256) {
    int r = idx >> 4, c4 = (idx & 15)*4;
    int gr = n0 - 1 + r;
    float4 v = make_float4(0.f,0.f,0.f,0.f);
    if (gr >= 0 && gr < LL) v = ld4(hin + ((size_t)b*LL + gr)*64 + c4);
    st4(&Ts[r][c4], v);
  }
  __syncthreads();
  int m = t & 15, rb = t >> 4;
  int co0 = m*4, r0 = rb*4;
  float acc[4][4] = {};
  for (int cc = 0; cc < 192; ++cc) {
    int kh = cc >> 6, ci = cc & 63;
    float4 w = ld4(&Ws[cc][co0]);
    #pragma unroll
    for (int i = 0; i < 4; ++i) {
      float xv = Ts[r0 + i + kh][ci];
      acc[i][0] = fmaf(xv, w.x, acc[i][0]);
      acc[i][1] = fmaf(xv, w.y, acc[i][1]);
      acc[i][2] = fmaf(xv, w.z, acc[i][2]);
      acc[i][3] = fmaf(xv, w.w, acc[i][3]);
    }
  }
  #pragma unroll
  for (int i = 0; i < 4; ++i)
    st4(hout + ((size_t)b*LL + n0 + r0 + i)*64 + co0,
        make_float4(acc[i][0],acc[i][1],acc[i][2],acc[i][3]));
}

// ---------------- generic 64->64 GEMM + bias ----------------
__global__ __launch_bounds__(256) void k_gemm64_bias(cfp X, cfp W, cfp bias, fp Y) {
  __shared__ float Xs[64][68], Ws[64][68];
  int t = threadIdx.x; size_t n0 = (size_t)blockIdx.x*64;
  load_tile64(X + n0*64, Xs, t);
  load_tile64(W, Ws, t);
  __syncthreads();
  int m = t&15, rb = t>>4, d0 = m*4, r0 = rb*4;
  float acc[4][4] = {};
  mm64(Xs, Ws, r0, d0, acc);
  float4 bv = ld4(bias + d0);
  #pragma unroll
  for (int i = 0; i < 4; ++i)
    st4(Y + (n0 + r0 + i)*64 + d0,
        make_float4(acc[i][0]+bv.x, acc[i][1]+bv.y, acc[i][2]+bv.z, acc[i][3]+bv.w));
}

// ---------------- agent attention: softmax over L, weighted V sum ----------------
__global__ __launch_bounds__(256) void k_agent(cfp h, cfp v, cfp anb, cfp means, fp agv) {
  int b = blockIdx.x, hh = blockIdx.y, t = threadIdx.x;
  __shared__ float sv[4096];
  __shared__ float red[256];
  __shared__ float redw[4][8];
  float ag[8];
  #pragma unroll
  for (int d = 0; d < 8; ++d) ag[d] = means[b*64 + hh*8 + d];
  const float scale = 0.35355339059327373f;  // 8^-0.5
  const float* hb = h + (size_t)b*LL*64 + hh*8;
  const float* anbb = anb + (size_t)hh*4096;
  float lm = -1e30f;
  for (int n = t; n < 4096; n += 256) {
    const float* hp = hb + (size_t)n*64;
    float4 a = ld4(hp), c = ld4(hp+4);
    float sc = ag[0]*a.x+ag[1]*a.y+ag[2]*a.z+ag[3]*a.w
             + ag[4]*c.x+ag[5]*c.y+ag[6]*c.z+ag[7]*c.w;
    sc = sc*scale + anbb[n];
    sv[n] = sc; lm = fmaxf(lm, sc);
  }
  red[t] = lm; __syncthreads();
  for (int off = 128; off > 0; off >>= 1) { if (t < off) red[t] = fmaxf(red[t], red[t+off]); __syncthreads(); }
  float M = red[0]; __syncthreads();
  float lsum = 0.f;
  for (int n = t; n < 4096; n += 256) { float p = __expf(sv[n]-M); sv[n] = p; lsum += p; }
  red[t] = lsum; __syncthreads();
  for (int off = 128; off > 0; off >>= 1) { if (t < off) red[t] += red[t+off]; __syncthreads(); }
  float rS = 1.f / red[0];
  float va[8] = {};
  const float* vb = v + (size_t)b*LL*64 + hh*8;
  for (int n = t; n < 4096; n += 256) {
    float p = sv[n];
    const float* vp = vb + (size_t)n*64;
    float4 a = ld4(vp), c = ld4(vp+4);
    va[0]+=p*a.x; va[1]+=p*a.y; va[2]+=p*a.z; va[3]+=p*a.w;
    va[4]+=p*c.x; va[5]+=p*c.y; va[6]+=p*c.z; va[7]+=p*c.w;
  }
  #pragma unroll
  for (int d = 0; d < 8; ++d) {
    float xx = va[d];
    #pragma unroll
    for (int off = 32; off > 0; off >>= 1) xx += __shfl_down(xx, off);
    if ((t & 63) == 0) redw[t >> 6][d] = xx;
  }
  __syncthreads();
  if (t < 8) agv[(b*8 + hh)*8 + t] = (redw[0][t]+redw[1][t]+redw[2][t]+redw[3][t]) * rS;
}

// ================= fused layer kernel =================
// Per 64-row tile (= one attention window):
//   QKV GEMMs -> wave-per-head windowed attention -> O@Wo + bo + agent + h + lepe
//   -> LN1 (kept in LDS) -> FFN(64->128->64, two 64-col halves) + residual -> LN2 -> Y
// LDS carve: Hs(h tile, later h1) | Abuf(W stage / Qs) | Bbuf(Ks / Os / W2h) | Cbuf(Vs / Hid)
__global__ __launch_bounds__(256, 2) void k_layer(
    cfp h, cfp vg, cfp agvp,
    cfp Wq, cfp bq, cfp Wk, cfp bk, cfp Wv, cfp bv, cfp Wo, cfp bo,
    cfp g1, cfp be1, cfp W1, cfp b1, cfp W2, cfp b2, cfp g2, cfp be2,
    fp Y) {
  __shared__ float Hs[64][68];        // 4352 f
  __shared__ float Abuf[4352];
  __shared__ float Bbuf[4352];
  __shared__ float Cbuf[4352];
  __shared__ float psum[64][17], pssq[64][17];
  __shared__ float mu[64], rs[64];    // total 19712 f = 78848 B -> 2 blocks/CU

  int t = threadIdx.x;
  size_t n0 = (size_t)blockIdx.x*64;
  int b = (int)(n0 >> 12);
  int m = t & 15, rb = t >> 4, d0 = m*4, r0 = rb*4;
  int hh4 = d0 >> 4, dih = d0 & 15;   // head / dim-in-head of this thread's output cols
  float (*A68)[68] = (float(*)[68])Abuf;
  float (*B68)[68] = (float(*)[68])Bbuf;
  float (*C68)[68] = (float(*)[68])Cbuf;

  load_tile64(h + n0*64, Hs, t);

  // ---- K = h@Wk + bk -> Bbuf [4][64][16] ----
  load_tile64(Wk, A68, t);
  __syncthreads();
  {
    float acc[4][4] = {};
    mm64(Hs, A68, r0, d0, acc);
    float4 b4 = ld4(bk + d0);
    float* dst = Bbuf + hh4*1024 + dih;
    #pragma unroll
    for (int i = 0; i < 4; ++i)
      st4(dst + (r0+i)*16, make_float4(acc[i][0]+b4.x, acc[i][1]+b4.y,
                                       acc[i][2]+b4.z, acc[i][3]+b4.w));
  }
  __syncthreads();
  // ---- V = h@Wv + bv -> Cbuf [4][64][16] ----
  load_tile64(Wv, A68, t);
  __syncthreads();
  {
    float acc[4][4] = {};
    mm64(Hs, A68, r0, d0, acc);
    float4 b4 = ld4(bv + d0);
    float* dst = Cbuf + hh4*1024 + dih;
    #pragma unroll
    for (int i = 0; i < 4; ++i)
      st4(dst + (r0+i)*16, make_float4(acc[i][0]+b4.x, acc[i][1]+b4.y,
                                       acc[i][2]+b4.z, acc[i][3]+b4.w));
  }
  __syncthreads();
  // ---- Q = h@Wq + bq -> Abuf [4][64][17] (odd stride: conflict-free per-lane rows) ----
  load_tile64(Wq, A68, t);
  __syncthreads();
  {
    float qacc[4][4] = {};
    mm64(Hs, A68, r0, d0, qacc);
    __syncthreads();               // everyone done reading Wq before overwrite
    float4 b4 = ld4(bq + d0);
    const float bq4[4] = {b4.x, b4.y, b4.z, b4.w};
    #pragma unroll
    for (int i = 0; i < 4; ++i)
      #pragma unroll
      for (int j = 0; j < 4; ++j)
        Abuf[hh4*1088 + (r0+i)*17 + dih + j] = qacc[i][j] + bq4[j];
  }
  __syncthreads();

  // ---- windowed attention: wave = head, lane = query row; softmax lane-local ----
  {
    int hh = t >> 6, lane = t & 63;
    const float* Qrow = Abuf + hh*1088 + lane*17;
    const float* Kh = Bbuf + hh*1024;
    const float* Vh = Cbuf + hh*1024;
    float q[16];
    #pragma unroll
    for (int d = 0; d < 16; ++d) q[d] = Qrow[d];
    float s[64]; float M = -1e30f;
    #pragma unroll
    for (int j = 0; j < 64; ++j) {
      const float* kp = Kh + j*16;
      float4 a0 = ld4(kp), a1 = ld4(kp+4), a2 = ld4(kp+8), a3 = ld4(kp+12);
      float dt = q[0]*a0.x + q[1]*a0.y + q[2]*a0.z + q[3]*a0.w
               + q[4]*a1.x + q[5]*a1.y + q[6]*a1.z + q[7]*a1.w
               + q[8]*a2.x + q[9]*a2.y + q[10]*a2.z + q[11]*a2.w
               + q[12]*a3.x + q[13]*a3.y + q[14]*a3.z + q[15]*a3.w;
      s[j] = dt * 0.25f;
      M = fmaxf(M, s[j]);
    }
    float l = 0.f;
    #pragma unroll
    for (int j = 0; j < 64; ++j) { s[j] = __expf(s[j] - M); l += s[j]; }
    float o[16] = {};
    #pragma unroll
    for (int j = 0; j < 64; ++j) {
      const float* vp = Vh + j*16;
      float4 a0 = ld4(vp), a1 = ld4(vp+4), a2 = ld4(vp+8), a3 = ld4(vp+12);
      float p = s[j];
      o[0]  = fmaf(p, a0.x, o[0]);  o[1]  = fmaf(p, a0.y, o[1]);
      o[2]  = fmaf(p, a0.z, o[2]);  o[3]  = fmaf(p, a0.w, o[3]);
      o[4]  = fmaf(p, a1.x, o[4]);  o[5]  = fmaf(p, a1.y, o[5]);
      o[6]  = fmaf(p, a1.z, o[6]);  o[7]  = fmaf(p, a1.w, o[7]);
      o[8]  = fmaf(p, a2.x, o[8]);  o[9]  = fmaf(p, a2.y, o[9]);
      o[10] = fmaf(p, a2.z, o[10]); o[11] = fmaf(p, a2.w, o[11]);
      o[12] = fmaf(p, a3.x, o[12]); o[13] = fmaf(p, a3.y, o[13]);
      o[14] = fmaf(p, a3.z, o[14]); o[15] = fmaf(p, a3.w, o[15]);
    }
    float rl = 1.f / l;
    __syncthreads();               // Ks/Vs/Qs reads done everywhere
    int hc = hh*16;
    #pragma unroll
    for (int k4 = 0; k4 < 4; ++k4)
      st4(&B68[lane][hc + k4*4],
          make_float4(o[k4*4]*rl, o[k4*4+1]*rl, o[k4*4+2]*rl, o[k4*4+3]*rl));
    load_tile64(Wo, A68, t);       // Qs consumed; stage Wo
  }
  __syncthreads();

  // ---- O@Wo + bo + agent + residual(h) + lepe(vg) -> LN1 (into Hs) ----
  {
    float acc[4][4] = {};
    mm64(B68, A68, r0, d0, acc);
    float4 bo4 = ld4(bo + d0);
    float4 ag4 = ld4(agvp + b*64 + d0);
    float comb[4][4];
    #pragma unroll
    for (int i = 0; i < 4; ++i) {
      size_t row = n0 + r0 + i;
      float4 vv = ld4(vg + row*64 + d0);
      comb[i][0] = acc[i][0]+bo4.x+ag4.x+Hs[r0+i][d0+0]+vv.x;
      comb[i][1] = acc[i][1]+bo4.y+ag4.y+Hs[r0+i][d0+1]+vv.y;
      comb[i][2] = acc[i][2]+bo4.z+ag4.z+Hs[r0+i][d0+2]+vv.z;
      comb[i][3] = acc[i][3]+bo4.w+ag4.w+Hs[r0+i][d0+3]+vv.w;
    }
    row_ln_lds(comb, r0, m, t, psum, pssq, mu, rs, g1, be1, Hs, d0);
  }

  // ---- FFN: two 64-wide halves of DFF=128; acc2 accumulates the 64-dim output ----
  float acc2[4][4] = {};
  #pragma unroll 1
  for (int p = 0; p < 2; ++p) {
    // stage W1[:, p*64 .. p*64+63] into A
    for (int idx = t; idx < 1024; idx += 256) {
      int c = idx >> 4, f4 = (idx & 15)*4;
      st4(&A68[c][f4], ld4(W1 + c*128 + p*64 + f4));
    }
    __syncthreads();               // h1(Hs) + W1 half ready
    {
      float aH[4][4] = {};
      mm64(Hs, A68, r0, d0, aH);
      float4 b4 = ld4(b1 + p*64 + d0);
      #pragma unroll
      for (int i = 0; i < 4; ++i)
        st4(&C68[r0+i][d0], make_float4(fmaxf(aH[i][0]+b4.x, 0.f), fmaxf(aH[i][1]+b4.y, 0.f),
                                        fmaxf(aH[i][2]+b4.z, 0.f), fmaxf(aH[i][3]+b4.w, 0.f)));
    }
    // stage W2[p*64 .. p*64+63, :] into B
    for (int idx = t; idx < 1024; idx += 256) {
      int f = idx >> 4, d4 = (idx & 15)*4;
      st4(&B68[f][d4], ld4(W2 + (size_t)(p*64 + f)*64 + d4));
    }
    __syncthreads();               // Hid + W2 half ready
    mm64(C68, B68, r0, d0, acc2);
    __syncthreads();               // B/C free for next half
  }
  {
    float4 b4 = ld4(b2 + d0);
    float comb[4][4];
    #pragma unroll
    for (int i = 0; i < 4; ++i) {
      comb[i][0] = acc2[i][0]+b4.x+Hs[r0+i][d0+0];
      comb[i][1] = acc2[i][1]+b4.y+Hs[r0+i][d0+1];
      comb[i][2] = acc2[i][2]+b4.z+Hs[r0+i][d0+2];
      comb[i][3] = acc2[i][3]+b4.w+Hs[r0+i][d0+3];
    }
    row_ln_write(comb, r0, m, t, psum, pssq, mu, rs, g2, be2, Y, n0, d0);
  }
}

extern "C" void kernel_launch(void* const* d_in, const int* in_sizes, int n_in,
                              void* d_out, int out_size, void* d_ws, size_t ws_size,
                              hipStream_t stream) {
  (void)in_sizes; (void)n_in; (void)out_size; (void)ws_size;
  const float* x    = (const float*)d_in[0];
  const float* dck  = (const float*)d_in[1];
  const float* dcw1 = (const float*)d_in[2];
  const float* dcb1 = (const float*)d_in[3];
  const float* dcw2 = (const float*)d_in[4];
  const float* dcb2 = (const float*)d_in[5];
  const float* embw = (const float*)d_in[6];
  const float* embb = (const float*)d_in[7];
  const float* getvw= (const float*)d_in[8];
  const float* getvb= (const float*)d_in[9];
  const float* anb  = (const float*)d_in[10];
  // d_in[11] = na_bias: provably unused (softmax over size-1 axis == 1)
  const float* wq = (const float*)d_in[12]; const float* bq = (const float*)d_in[13];
  const float* wk = (const float*)d_in[14]; const float* bk = (const float*)d_in[15];
  const float* wv = (const float*)d_in[16]; const float* bv = (const float*)d_in[17];
  const float* wo = (const float*)d_in[18]; const float* bo = (const float*)d_in[19];
  const float* fw1= (const float*)d_in[20]; const float* fb1= (const float*)d_in[21];
  const float* fw2= (const float*)d_in[22]; const float* fb2= (const float*)d_in[23];
  const float* g1 = (const float*)d_in[24]; const float* be1= (const float*)d_in[25];
  const float* g2 = (const float*)d_in[26]; const float* be2= (const float*)d_in[27];

  float* out = (float*)d_out;
  float* ws  = (float*)d_ws;
  const size_t SZ = (size_t)BB*LL*DD;   // 4,194,304 floats
  float* bufA = ws;
  float* bufB = ws + SZ;
  float* vbuf = ws + 2*SZ;
  float* pp    = ws + 3*SZ;
  float* means = pp + BB*16*64;
  float* agv   = means + BB*64;
  float* wef   = agv + BB*64;

  dim3 blk(256);
  const int NT = BB*LL/64;  // 1024 row-tiles

  // ---- dynamic conv stem (3 stages) ----
  const float* cin = x;
  float* cout = bufA;
  for (int i = 0; i < 3; ++i) {
    k_pool_part<<<dim3(BB,16), blk, 0, stream>>>(cin, pp);
    k_pool_fin<<<BB, 64, 0, stream>>>(pp, means);
    k_weff<<<BB, blk, 0, stream>>>(means, dcw1 + i*16*64, dcb1 + i*16,
                                   dcw2 + i*3*16, dcb2 + i*3,
                                   dck + (size_t)i*3*64*64*9, wef);
    k_conv<<<dim3(BB,64), blk, 0, stream>>>(cin, wef, cout);
    cin = cout;
    cout = (cout == bufA) ? bufB : bufA;
  }
  // cin == bufA after 3 stages; embed into bufB
  k_gemm64_bias<<<NT, blk, 0, stream>>>(cin, embw, embb, bufB);

  float* h  = bufB;
  float* hn = bufA;
  for (int i = 0; i < 3; ++i) {
    k_pool_part<<<dim3(BB,16), blk, 0, stream>>>(h, pp);
    k_pool_fin<<<BB, 64, 0, stream>>>(pp, means);
    k_gemm64_bias<<<NT, blk, 0, stream>>>(h, getvw + i*4096, getvb + i*64, vbuf);
    k_agent<<<dim3(BB,8), blk, 0, stream>>>(h, vbuf, anb + (size_t)i*8*4096, means, agv);
    float* dst = (i == 2) ? out : hn;
    k_layer<<<NT, blk, 0, stream>>>(h, vbuf, agv,
                                    wq + i*4096, bq + i*64, wk + i*4096, bk + i*64,
                                    wv + i*4096, bv + i*64, wo + i*4096, bo + i*64,
                                    g1 + i*64, be1 + i*64,
                                    fw1 + (size_t)i*64*128, fb1 + i*128,
                                    fw2 + (size_t)i*128*64, fb2 + i*64,
                                    g2 + i*64, be2 + i*64, dst);
    float* tmp = h; h = hn; hn = tmp;
  }
}

// Round 3
// 482.901 us; speedup vs baseline: 1.9148x; 1.4928x over previous
//
#include <hip/hip_runtime.h>

#define BB 16
#define LL 4096
#define DD 64

typedef const float* __restrict__ cfp;
typedef float* __restrict__ fp;

typedef __attribute__((ext_vector_type(8))) short bf16x8;
typedef __attribute__((ext_vector_type(4))) float f32x4;
#define MFMA16(a, b, c) __builtin_amdgcn_mfma_f32_16x16x32_bf16(a, b, c, 0, 0, 0)

__device__ __forceinline__ float4 ld4(const float* p){ return *reinterpret_cast<const float4*>(p); }
__device__ __forceinline__ void st4(float* p, float4 v){ *reinterpret_cast<float4*>(p) = v; }

__device__ __forceinline__ ushort f2bf(float f){
  uint u = __float_as_uint(f);
  return (ushort)((u + 0x7FFFu + ((u >> 16) & 1u)) >> 16);   // RNE
}
__device__ __forceinline__ uint packf2(float a, float b){
  return (uint)f2bf(a) | ((uint)f2bf(b) << 16);
}
__device__ __forceinline__ uint2 pack4(float4 v){
  return make_uint2(packf2(v.x, v.y), packf2(v.z, v.w));
}
__device__ __forceinline__ bf16x8 ldfrag(const ushort* p){ return *reinterpret_cast<const bf16x8*>(p); }

// ---------------- fp32 helpers (kept for emb GEMM) ----------------
__device__ __forceinline__ void load_tile64(const float* __restrict__ g, float (*S)[68], int t){
  #pragma unroll
  for (int it = 0; it < 4; ++it) {
    int idx = it*256 + t;
    int r = idx >> 4, c4 = (idx & 15) << 2;
    st4(&S[r][c4], ld4(g + (size_t)r*64 + c4));
  }
}
__device__ __forceinline__ void mm64(const float (*Xs)[68], const float (*Ws)[68],
                                     int r0, int d0, float acc[4][4]){
  for (int c = 0; c < 64; ++c) {
    float4 w = ld4(&Ws[c][d0]);
    #pragma unroll
    for (int i = 0; i < 4; ++i) {
      float xv = Xs[r0+i][c];
      acc[i][0] = fmaf(xv, w.x, acc[i][0]);
      acc[i][1] = fmaf(xv, w.y, acc[i][1]);
      acc[i][2] = fmaf(xv, w.z, acc[i][2]);
      acc[i][3] = fmaf(xv, w.w, acc[i][3]);
    }
  }
}

// ---------------- weight packing into bf16 B-fragments ----------------
// per layer: wq@0, wk@4096, wv@8192, getv@12288, wo@16384, fw1@20480, fw2@28672 (36864 total)
__global__ __launch_bounds__(256) void k_pack(cfp wq, cfp wk, cfp wv, cfp getv, cfp wo,
                                              cfp fw1, cfp fw2, ushort* __restrict__ dst) {
  int layer = blockIdx.y;
  int e = blockIdx.x*256 + threadIdx.x;        // e < 36864
  const float* W; int N, rem;
  if (e < 20480) {
    int mm = e >> 12; rem = e & 4095;
    W = (mm==0?wq: mm==1?wk: mm==2?wv: mm==3?getv: wo) + layer*4096; N = 64;
  } else if (e < 28672) {
    rem = e - 20480; W = fw1 + layer*8192; N = 128;
  } else {
    rem = e - 28672; W = fw2 + layer*8192; N = 64;
  }
  int NT = N >> 4;
  int j = rem & 7, lane = (rem >> 3) & 63, rest = rem >> 9;
  int nt = rest % NT, ks = rest / NT;
  int k = ks*32 + ((lane >> 4) << 3) + j, n = nt*16 + (lane & 15);
  dst[(size_t)layer*36864 + e] = f2bf(W[(size_t)k*N + n]);
}

// ---------------- pooling ----------------
__global__ __launch_bounds__(256) void k_pool_part(cfp h, fp pp) {
  int b = blockIdx.x, gblk = blockIdx.y, t = threadIdx.x;
  int c = t & 63, r = t >> 6;
  const float* base = h + ((size_t)b*LL + (size_t)gblk*256)*64;
  float acc = 0.f;
  for (int l = r; l < 256; l += 4) acc += base[(size_t)l*64 + c];
  __shared__ float red[4][64];
  red[r][c] = acc; __syncthreads();
  if (t < 64) pp[(b*16 + gblk)*64 + t] = red[0][t]+red[1][t]+red[2][t]+red[3][t];
}

__global__ void k_pool_fin(cfp pp, fp means, int chunks) {
  int b = blockIdx.x, c = threadIdx.x;
  float s = 0.f;
  for (int g = 0; g < chunks; ++g) s += pp[(b*chunks + g)*64 + c];
  means[b*64 + c] = s * (1.f/4096.f);
}

// ---------------- dynamic conv: attention + effective kernel (bf16 B-frags) ----------------
__global__ __launch_bounds__(256) void k_weff(cfp means, cfp w1, cfp b1, cfp w2, cfp b2,
                                              cfp kern, ushort* __restrict__ weffB) {
  int b = blockIdx.x, t = threadIdx.x;
  __shared__ float pooled[64], hdn[16], attn[3];
  if (t < 64) pooled[t] = means[b*64 + t];
  __syncthreads();
  if (t < 16) {
    float a = b1[t];
    for (int c = 0; c < 64; ++c) a += pooled[c]*w1[t*64 + c];
    hdn[t] = fmaxf(a, 0.f);
  }
  __syncthreads();
  if (t < 3) {
    float a = b2[t];
    for (int j = 0; j < 16; ++j) a += hdn[j]*w2[t*16 + j];
    attn[t] = a;
  }
  __syncthreads();
  if (t == 0) {
    float m = fmaxf(attn[0], fmaxf(attn[1], attn[2]));
    float e0 = __expf(attn[0]-m), e1 = __expf(attn[1]-m), e2 = __expf(attn[2]-m);
    float s = e0+e1+e2;
    attn[0]=e0/s; attn[1]=e1/s; attn[2]=e2/s;
  }
  __syncthreads();
  float a0=attn[0], a1=attn[1], a2=attn[2];
  for (int e = t; e < 12288; e += 256) {
    int j = e & 7, lane = (e >> 3) & 63, nt = (e >> 9) & 3, ks = e >> 11;
    int k = ks*32 + ((lane >> 4) << 3) + j;
    int co = nt*16 + (lane & 15);
    int kh = k >> 6, ci = k & 63;
    size_t base = ((size_t)co*64 + ci)*9 + kh*3 + 1;     // kw=1 only (W=1 with pad)
    float v = a0*kern[base] + a1*kern[base + 36864] + a2*kern[base + 2*36864];
    weffB[(size_t)b*12288 + e] = f2bf(v);
  }
}

// ---------------- 3-tap conv along L as K=192 MFMA GEMM ----------------
__global__ __launch_bounds__(256) void k_conv(cfp hin, const ushort* __restrict__ weffB,
                                              fp hout, fp pp) {
  int b = blockIdx.x, wblk = blockIdx.y, t = threadIdx.x;
  int n0 = wblk*64;
  __shared__ ushort Ts[66*72];          // rows n0-1..n0+64 bf16, stride 72 (144B, 16B-aligned)
  __shared__ float red[64*17];
  for (int idx = t; idx < 1056; idx += 256) {
    int r = idx >> 4, c4 = (idx & 15)*4, gr = n0 - 1 + r;
    float4 v = make_float4(0.f,0.f,0.f,0.f);
    if (gr >= 0 && gr < LL) v = ld4(hin + ((size_t)b*LL + gr)*64 + c4);
    *(uint2*)(Ts + r*72 + c4) = pack4(v);
  }
  __syncthreads();
  int w = t >> 6, l = t & 63, band = w*16, lr = l & 15, lg = l >> 4;
  const ushort* wb = weffB + (size_t)b*12288;
  f32x4 acc[4];
  #pragma unroll
  for (int nt = 0; nt < 4; ++nt) acc[nt] = (f32x4){0.f,0.f,0.f,0.f};
  #pragma unroll
  for (int ks = 0; ks < 6; ++ks) {
    int k8 = ks*32 + lg*8;
    int kh = k8 >> 6, ci = k8 & 63;
    bf16x8 a = ldfrag(Ts + (band + lr + kh)*72 + ci);
    #pragma unroll
    for (int nt = 0; nt < 4; ++nt)
      acc[nt] = MFMA16(a, ldfrag(wb + ((ks*4+nt)*64 + l)*8), acc[nt]);
  }
  #pragma unroll
  for (int nt = 0; nt < 4; ++nt) {
    int co = nt*16 + lr;
    float part = 0.f;
    #pragma unroll
    for (int reg = 0; reg < 4; ++reg) {
      int row = band + lg*4 + reg;
      float v = acc[nt][reg];
      hout[((size_t)b*LL + n0 + row)*64 + co] = v;
      part += v;
    }
    red[co*17 + w*4 + lg] = part;
  }
  __syncthreads();
  if (t < 64) {
    float s = 0.f;
    #pragma unroll
    for (int g = 0; g < 16; ++g) s += red[t*17 + g];
    pp[((size_t)b*64 + wblk)*64 + t] = s;
  }
}

// ---------------- emb GEMM (fp32) + pooling emission ----------------
__global__ __launch_bounds__(256) void k_gemm64_bias(cfp X, cfp W, cfp bias, fp Y, fp pp) {
  __shared__ float Xs[64][68], Ws[64][68];
  __shared__ float red[64*17];
  int t = threadIdx.x; size_t n0 = (size_t)blockIdx.x*64;
  load_tile64(X + n0*64, Xs, t);
  load_tile64(W, Ws, t);
  __syncthreads();
  int m = t&15, rb = t>>4, d0 = m*4, r0 = rb*4;
  float acc[4][4] = {};
  mm64(Xs, Ws, r0, d0, acc);
  float4 bv = ld4(bias + d0);
  const float b4[4] = {bv.x, bv.y, bv.z, bv.w};
  #pragma unroll
  for (int i = 0; i < 4; ++i)
    st4(Y + (n0 + r0 + i)*64 + d0,
        make_float4(acc[i][0]+b4[0], acc[i][1]+b4[1], acc[i][2]+b4[2], acc[i][3]+b4[3]));
  #pragma unroll
  for (int j = 0; j < 4; ++j)
    red[(d0+j)*17 + rb] = acc[0][j]+acc[1][j]+acc[2][j]+acc[3][j] + 4.f*b4[j];
  __syncthreads();
  if (t < 64) {
    float s = 0.f;
    #pragma unroll
    for (int g = 0; g < 16; ++g) s += red[t*17 + g];
    pp[(size_t)blockIdx.x*64 + t] = s;
  }
}

// ---------------- agent attention (agent_v via linearity: (a.H)@getv + b) ----------------
__global__ __launch_bounds__(256) void k_agent(cfp h, cfp anb, cfp means,
                                               cfp getv, cfp getvb, fp agv) {
  int b = blockIdx.x, hh = blockIdx.y, t = threadIdx.x;
  __shared__ float sv[4096];
  __shared__ float red[256];
  __shared__ float wred[4][64];
  __shared__ float whs[64];
  float ag[8];
  #pragma unroll
  for (int d = 0; d < 8; ++d) ag[d] = means[b*64 + hh*8 + d];
  const float scale = 0.35355339059327373f;  // 8^-0.5
  const float* hb = h + (size_t)b*LL*64;
  const float* anbb = anb + (size_t)hh*LL;
  float lm = -1e30f;
  for (int n = t; n < 4096; n += 256) {
    const float* hp = hb + (size_t)n*64 + hh*8;
    float4 a = ld4(hp), c = ld4(hp+4);
    float sc = ag[0]*a.x+ag[1]*a.y+ag[2]*a.z+ag[3]*a.w
             + ag[4]*c.x+ag[5]*c.y+ag[6]*c.z+ag[7]*c.w;
    sc = sc*scale + anbb[n];
    sv[n] = sc; lm = fmaxf(lm, sc);
  }
  red[t] = lm; __syncthreads();
  for (int off = 128; off > 0; off >>= 1) { if (t < off) red[t] = fmaxf(red[t], red[t+off]); __syncthreads(); }
  float M = red[0]; __syncthreads();
  float lsum = 0.f;
  for (int n = t; n < 4096; n += 256) { float p = __expf(sv[n]-M); sv[n] = p; lsum += p; }
  red[t] = lsum; __syncthreads();
  for (int off = 128; off > 0; off >>= 1) { if (t < off) red[t] += red[t+off]; __syncthreads(); }
  float rS = 1.f / red[0];
  // weighted mean of h rows (coalesced: lane owns one dim)
  int l = t & 63, g = t >> 6;
  const float* hb2 = hb + l;
  float wa = 0.f;
  for (int n = g; n < 4096; n += 16) {
    wa += sv[n]      * hb2[(size_t)n*64];
    wa += sv[n+4]    * hb2[(size_t)(n+4)*64];
    wa += sv[n+8]    * hb2[(size_t)(n+8)*64];
    wa += sv[n+12]   * hb2[(size_t)(n+12)*64];
  }
  wred[g][l] = wa;
  __syncthreads();
  if (t < 64) whs[t] = (wred[0][t]+wred[1][t]+wred[2][t]+wred[3][t]) * rS;
  __syncthreads();
  if (t < 8) {
    float a = getvb[hh*8 + t];
    for (int c = 0; c < 64; ++c) a += whs[c] * getv[c*64 + hh*8 + t];
    agv[(b*8 + hh)*8 + t] = a;
  }
}

// ================= fused layer kernel (MFMA GEMMs) =================
__global__ __launch_bounds__(256, 2) void k_layer(
    cfp h, cfp agvp, const ushort* __restrict__ wB,
    cfp bq, cfp bk, cfp bv, cfp getvb, cfp bo,
    cfp g1, cfp be1, cfp b1, cfp b2, cfp g2, cfp be2,
    fp Y, fp pp) {
  __shared__ float smem[19200];                  // 76800 B -> 2 blocks/CU
  float*  Hs   = smem;                           // [64][68] fp32 h tile -> h1
  ushort* HsB  = (ushort*)(smem + 4352);         // [64][72] bf16 A-operand
  float*  Kb   = smem + 6656;                    // [4][64][16]
  float*  Vb   = smem + 10752;                   // [4][64][16]
  ushort* HidB = (ushort*)(smem + 6656);         // [64][136] (aliases Kb+Vb head)
  float*  red  = smem + 11008;                   // [64][17]  (aliases Vb tail, after HidB)
  float*  Qb   = smem + 14848;                   // [4][64][17]
  ushort* OB   = (ushort*)(smem + 14848);        // [64][72]  (aliases Qb)

  int t = threadIdx.x;
  size_t n0 = (size_t)blockIdx.x*64;
  int b = (int)(n0 >> 12);
  int w = t >> 6, l = t & 63, band = w*16, lr = l & 15, lg = l >> 4;

  // stage h tile: fp32 + bf16
  #pragma unroll
  for (int it = 0; it < 4; ++it) {
    int idx = it*256 + t, r = idx >> 4, c4 = (idx & 15)*4;
    float4 v = ld4(h + (n0 + r)*64 + c4);
    st4(&Hs[r*68 + c4], v);
    *(uint2*)(HsB + r*72 + c4) = pack4(v);
  }
  __syncthreads();

  // ---- K,V,Q,lepe MFMA GEMMs (A = HsB, B = packed global frags) ----
  f32x4 ka[4], va[4], qa[4], la[4];
  #pragma unroll
  for (int nt = 0; nt < 4; ++nt) {
    ka[nt] = (f32x4){0.f,0.f,0.f,0.f}; va[nt] = (f32x4){0.f,0.f,0.f,0.f};
    qa[nt] = (f32x4){0.f,0.f,0.f,0.f}; la[nt] = (f32x4){0.f,0.f,0.f,0.f};
  }
  #pragma unroll
  for (int ks = 0; ks < 2; ++ks) {
    bf16x8 a = ldfrag(HsB + (band + lr)*72 + ks*32 + lg*8);
    #pragma unroll
    for (int nt = 0; nt < 4; ++nt) {
      int fo = ((ks*4 + nt)*64 + l)*8;
      qa[nt] = MFMA16(a, ldfrag(wB + fo),         qa[nt]);
      ka[nt] = MFMA16(a, ldfrag(wB + 4096 + fo),  ka[nt]);
      va[nt] = MFMA16(a, ldfrag(wB + 8192 + fo),  va[nt]);
      la[nt] = MFMA16(a, ldfrag(wB + 12288 + fo), la[nt]);
    }
  }
  #pragma unroll
  for (int nt = 0; nt < 4; ++nt) {
    int col = nt*16 + lr;
    float bkc = bk[col], bvc = bv[col], bqc = bq[col];
    #pragma unroll
    for (int reg = 0; reg < 4; ++reg) {
      int row = band + lg*4 + reg;
      Kb[nt*1024 + row*16 + lr] = ka[nt][reg] + bkc;
      Vb[nt*1024 + row*16 + lr] = va[nt][reg] + bvc;
      Qb[nt*1088 + row*17 + lr] = qa[nt][reg] + bqc;
    }
  }
  __syncthreads();

  // ---- windowed attention: wave = head, lane = query row, softmax lane-local ----
  {
    const float* Qrow = Qb + w*1088 + l*17;
    const float* Kh = Kb + w*1024;
    const float* Vh = Vb + w*1024;
    float qv[16];
    #pragma unroll
    for (int d = 0; d < 16; ++d) qv[d] = Qrow[d];
    float s[64]; float M = -1e30f;
    #pragma unroll
    for (int j = 0; j < 64; ++j) {
      const float* kp = Kh + j*16;
      float4 a0 = ld4(kp), a1 = ld4(kp+4), a2 = ld4(kp+8), a3 = ld4(kp+12);
      float dt = qv[0]*a0.x + qv[1]*a0.y + qv[2]*a0.z + qv[3]*a0.w
               + qv[4]*a1.x + qv[5]*a1.y + qv[6]*a1.z + qv[7]*a1.w
               + qv[8]*a2.x + qv[9]*a2.y + qv[10]*a2.z + qv[11]*a2.w
               + qv[12]*a3.x + qv[13]*a3.y + qv[14]*a3.z + qv[15]*a3.w;
      s[j] = dt * 0.25f;
      M = fmaxf(M, s[j]);
    }
    float lsum = 0.f;
    #pragma unroll
    for (int j = 0; j < 64; ++j) { s[j] = __expf(s[j] - M); lsum += s[j]; }
    float o[16] = {};
    #pragma unroll
    for (int j = 0; j < 64; ++j) {
      const float* vp = Vh + j*16;
      float4 a0 = ld4(vp), a1 = ld4(vp+4), a2 = ld4(vp+8), a3 = ld4(vp+12);
      float p = s[j];
      o[0]  = fmaf(p, a0.x, o[0]);  o[1]  = fmaf(p, a0.y, o[1]);
      o[2]  = fmaf(p, a0.z, o[2]);  o[3]  = fmaf(p, a0.w, o[3]);
      o[4]  = fmaf(p, a1.x, o[4]);  o[5]  = fmaf(p, a1.y, o[5]);
      o[6]  = fmaf(p, a1.z, o[6]);  o[7]  = fmaf(p, a1.w, o[7]);
      o[8]  = fmaf(p, a2.x, o[8]);  o[9]  = fmaf(p, a2.y, o[9]);
      o[10] = fmaf(p, a2.z, o[10]); o[11] = fmaf(p, a2.w, o[11]);
      o[12] = fmaf(p, a3.x, o[12]); o[13] = fmaf(p, a3.y, o[13]);
      o[14] = fmaf(p, a3.z, o[14]); o[15] = fmaf(p, a3.w, o[15]);
    }
    float rl = 1.f / lsum;
    __syncthreads();              // all Q/K/V reads done before OB overwrites Qb
    ushort* obr = OB + l*72 + w*16;
    #pragma unroll
    for (int k2 = 0; k2 < 8; ++k2)
      *(uint*)(obr + k2*2) = packf2(o[2*k2]*rl, o[2*k2+1]*rl);
  }
  __syncthreads();

  // ---- O@Wo + bo + agent + residual(h) + lepe -> LN1 (frag space) ----
  float comb[4][4];
  {
    f32x4 wa[4];
    #pragma unroll
    for (int nt = 0; nt < 4; ++nt) wa[nt] = (f32x4){0.f,0.f,0.f,0.f};
    #pragma unroll
    for (int ks = 0; ks < 2; ++ks) {
      bf16x8 a = ldfrag(OB + (band + lr)*72 + ks*32 + lg*8);
      #pragma unroll
      for (int nt = 0; nt < 4; ++nt)
        wa[nt] = MFMA16(a, ldfrag(wB + 16384 + ((ks*4+nt)*64 + l)*8), wa[nt]);
    }
    #pragma unroll
    for (int nt = 0; nt < 4; ++nt) {
      int col = nt*16 + lr;
      float cadd = bo[col] + agvp[b*64 + col] + getvb[col];
      #pragma unroll
      for (int reg = 0; reg < 4; ++reg) {
        int row = band + lg*4 + reg;
        comb[nt][reg] = wa[nt][reg] + la[nt][reg] + cadd + Hs[row*68 + col];
      }
    }
  }
  {
    float mean1[4], rstd1[4];
    #pragma unroll
    for (int reg = 0; reg < 4; ++reg) {
      float s = comb[0][reg]+comb[1][reg]+comb[2][reg]+comb[3][reg];
      float qq = comb[0][reg]*comb[0][reg]+comb[1][reg]*comb[1][reg]
               + comb[2][reg]*comb[2][reg]+comb[3][reg]*comb[3][reg];
      s += __shfl_xor(s,1); qq += __shfl_xor(qq,1);
      s += __shfl_xor(s,2); qq += __shfl_xor(qq,2);
      s += __shfl_xor(s,4); qq += __shfl_xor(qq,4);
      s += __shfl_xor(s,8); qq += __shfl_xor(qq,8);
      float mn = s*0.015625f;
      mean1[reg] = mn;
      rstd1[reg] = rsqrtf(qq*0.015625f - mn*mn + 1e-5f);
    }
    #pragma unroll
    for (int nt = 0; nt < 4; ++nt) {
      int col = nt*16 + lr;
      float gg = g1[col], bb = be1[col];
      #pragma unroll
      for (int reg = 0; reg < 4; ++reg) {
        int row = band + lg*4 + reg;
        float h1 = (comb[nt][reg]-mean1[reg])*rstd1[reg]*gg + bb;
        Hs[row*68 + col] = h1;
        HsB[row*72 + col] = f2bf(h1);
      }
    }
  }
  __syncthreads();

  // ---- FFN1: h1 @ W1 (64->128) + relu -> HidB bf16 ----
  {
    f32x4 fa[8];
    #pragma unroll
    for (int nt = 0; nt < 8; ++nt) fa[nt] = (f32x4){0.f,0.f,0.f,0.f};
    #pragma unroll
    for (int ks = 0; ks < 2; ++ks) {
      bf16x8 a = ldfrag(HsB + (band + lr)*72 + ks*32 + lg*8);
      #pragma unroll
      for (int nt = 0; nt < 8; ++nt)
        fa[nt] = MFMA16(a, ldfrag(wB + 20480 + ((ks*8+nt)*64 + l)*8), fa[nt]);
    }
    #pragma unroll
    for (int nt = 0; nt < 8; ++nt) {
      int col = nt*16 + lr;
      float b1c = b1[col];
      #pragma unroll
      for (int reg = 0; reg < 4; ++reg) {
        int row = band + lg*4 + reg;
        HidB[row*136 + col] = f2bf(fmaxf(fa[nt][reg] + b1c, 0.f));
      }
    }
  }
  __syncthreads();

  // ---- FFN2: Hid @ W2 (128->64) + b2 + residual(h1) -> LN2 -> Y (+pool partials) ----
  {
    f32x4 f2[4];
    #pragma unroll
    for (int nt = 0; nt < 4; ++nt) f2[nt] = (f32x4){0.f,0.f,0.f,0.f};
    #pragma unroll
    for (int ks = 0; ks < 4; ++ks) {
      bf16x8 a = ldfrag(HidB + (band + lr)*136 + ks*32 + lg*8);
      #pragma unroll
      for (int nt = 0; nt < 4; ++nt)
        f2[nt] = MFMA16(a, ldfrag(wB + 28672 + ((ks*4+nt)*64 + l)*8), f2[nt]);
    }
    float c2[4][4];
    #pragma unroll
    for (int nt = 0; nt < 4; ++nt) {
      int col = nt*16 + lr;
      float b2c = b2[col];
      #pragma unroll
      for (int reg = 0; reg < 4; ++reg) {
        int row = band + lg*4 + reg;
        c2[nt][reg] = f2[nt][reg] + b2c + Hs[row*68 + col];
      }
    }
    float mean2[4], rstd2[4];
    #pragma unroll
    for (int reg = 0; reg < 4; ++reg) {
      float s = c2[0][reg]+c2[1][reg]+c2[2][reg]+c2[3][reg];
      float qq = c2[0][reg]*c2[0][reg]+c2[1][reg]*c2[1][reg]
               + c2[2][reg]*c2[2][reg]+c2[3][reg]*c2[3][reg];
      s += __shfl_xor(s,1); qq += __shfl_xor(qq,1);
      s += __shfl_xor(s,2); qq += __shfl_xor(qq,2);
      s += __shfl_xor(s,4); qq += __shfl_xor(qq,4);
      s += __shfl_xor(s,8); qq += __shfl_xor(qq,8);
      float mn = s*0.015625f;
      mean2[reg] = mn;
      rstd2[reg] = rsqrtf(qq*0.015625f - mn*mn + 1e-5f);
    }
    #pragma unroll
    for (int nt = 0; nt < 4; ++nt) {
      int col = nt*16 + lr;
      float gg = g2[col], bb = be2[col];
      float part = 0.f;
      #pragma unroll
      for (int reg = 0; reg < 4; ++reg) {
        int row = band + lg*4 + reg;
        float y = (c2[nt][reg]-mean2[reg])*rstd2[reg]*gg + bb;
        Y[(n0 + row)*64 + col] = y;
        part += y;
      }
      red[col*17 + w*4 + lg] = part;
    }
  }
  __syncthreads();
  if (t < 64) {
    float s = 0.f;
    #pragma unroll
    for (int g = 0; g < 16; ++g) s += red[t*17 + g];
    pp[(size_t)blockIdx.x*64 + t] = s;
  }
}

extern "C" void kernel_launch(void* const* d_in, const int* in_sizes, int n_in,
                              void* d_out, int out_size, void* d_ws, size_t ws_size,
                              hipStream_t stream) {
  (void)in_sizes; (void)n_in; (void)out_size; (void)ws_size;
  const float* x    = (const float*)d_in[0];
  const float* dck  = (const float*)d_in[1];
  const float* dcw1 = (const float*)d_in[2];
  const float* dcb1 = (const float*)d_in[3];
  const float* dcw2 = (const float*)d_in[4];
  const float* dcb2 = (const float*)d_in[5];
  const float* embw = (const float*)d_in[6];
  const float* embb = (const float*)d_in[7];
  const float* getvw= (const float*)d_in[8];
  const float* getvb= (const float*)d_in[9];
  const float* anb  = (const float*)d_in[10];
  // d_in[11] = na_bias: provably unused (softmax over size-1 axis == 1)
  const float* wq = (const float*)d_in[12]; const float* bq = (const float*)d_in[13];
  const float* wk = (const float*)d_in[14]; const float* bk = (const float*)d_in[15];
  const float* wv = (const float*)d_in[16]; const float* bv = (const float*)d_in[17];
  const float* wo = (const float*)d_in[18]; const float* bo = (const float*)d_in[19];
  const float* fw1= (const float*)d_in[20]; const float* fb1= (const float*)d_in[21];
  const float* fw2= (const float*)d_in[22]; const float* fb2= (const float*)d_in[23];
  const float* g1 = (const float*)d_in[24]; const float* be1= (const float*)d_in[25];
  const float* g2 = (const float*)d_in[26]; const float* be2= (const float*)d_in[27];

  float* out = (float*)d_out;
  float* ws  = (float*)d_ws;
  const size_t SZ = (size_t)BB*LL*DD;   // 4,194,304 floats
  float* bufA = ws;
  float* bufB = ws + SZ;
  float* pp    = ws + 2*SZ;                       // up to 64 chunks x 64 per batch
  float* means = pp + 65536;
  float* agv   = means + 1024;
  ushort* weffB = (ushort*)(agv + 1024);          // 16 x 12288 bf16
  ushort* wsB   = weffB + BB*12288;               // 3 x 36864 bf16

  dim3 blk(256);
  const int NT = BB*LL/64;  // 1024 row-tiles

  k_pack<<<dim3(144, 3), blk, 0, stream>>>(wq, wk, wv, getvw, wo, fw1, fw2, wsB);

  // ---- dynamic conv stem (3 stages) ----
  const float* cin = x;
  float* cout = bufA;
  for (int i = 0; i < 3; ++i) {
    if (i == 0) {
      k_pool_part<<<dim3(BB,16), blk, 0, stream>>>(x, pp);
      k_pool_fin<<<BB, 64, 0, stream>>>(pp, means, 16);
    } else {
      k_pool_fin<<<BB, 64, 0, stream>>>(pp, means, 64);
    }
    k_weff<<<BB, blk, 0, stream>>>(means, dcw1 + i*1024, dcb1 + i*16,
                                   dcw2 + i*48, dcb2 + i*3,
                                   dck + (size_t)i*110592, weffB);
    k_conv<<<dim3(BB,64), blk, 0, stream>>>(cin, weffB, cout, pp);
    cin = cout;
    cout = (cout == bufA) ? bufB : bufA;
  }
  // cin == bufA after 3 stages; embed into bufB (emits pooling partials for layer 1)
  k_gemm64_bias<<<NT, blk, 0, stream>>>(cin, embw, embb, bufB, pp);

  float* h  = bufB;
  float* hn = bufA;
  for (int i = 0; i < 3; ++i) {
    k_pool_fin<<<BB, 64, 0, stream>>>(pp, means, 64);
    k_agent<<<dim3(BB,8), blk, 0, stream>>>(h, anb + (size_t)i*8*4096, means,
                                            getvw + i*4096, getvb + i*64, agv);
    float* dst = (i == 2) ? out : hn;
    k_layer<<<NT, blk, 0, stream>>>(h, agv, wsB + (size_t)i*36864,
                                    bq + i*64, bk + i*64, bv + i*64, getvb + i*64, bo + i*64,
                                    g1 + i*64, be1 + i*64, fb1 + i*128, fb2 + i*64,
                                    g2 + i*64, be2 + i*64, dst, pp);
    float* tmp = h; h = hn; hn = tmp;
  }
}

// Round 5
// 336.266 us; speedup vs baseline: 2.7498x; 1.4361x over previous
//
#include <hip/hip_runtime.h>

#define BB 16
#define LL 4096
#define DD 64

typedef const float* __restrict__ cfp;
typedef float* __restrict__ fp;

typedef __attribute__((ext_vector_type(8))) short bf16x8;
typedef __attribute__((ext_vector_type(4))) float f32x4;
#define MFMA16(a, b, c) __builtin_amdgcn_mfma_f32_16x16x32_bf16(a, b, c, 0, 0, 0)

__device__ __forceinline__ f32x4 zf4(){ f32x4 z; z[0]=0.f; z[1]=0.f; z[2]=0.f; z[3]=0.f; return z; }

union frag_u { bf16x8 v; uint2 u2[2]; uint u[4]; };

__device__ __forceinline__ float4 ld4(const float* p){ return *reinterpret_cast<const float4*>(p); }
__device__ __forceinline__ void st4(float* p, float4 v){ *reinterpret_cast<float4*>(p) = v; }

__device__ __forceinline__ ushort f2bf(float f){
  uint u = __float_as_uint(f);
  return (ushort)((u + 0x7FFFu + ((u >> 16) & 1u)) >> 16);   // RNE
}
__device__ __forceinline__ uint packf2(float a, float b){
  return (uint)f2bf(a) | ((uint)f2bf(b) << 16);
}
__device__ __forceinline__ uint2 pack4(float4 v){
  return make_uint2(packf2(v.x, v.y), packf2(v.z, v.w));
}
__device__ __forceinline__ bf16x8 ldfrag(const ushort* p){ return *reinterpret_cast<const bf16x8*>(p); }

// ---------------- weight packing into bf16 B-fragments ----------------
// per layer: wq@0, wk@4096, wv@8192, getv@12288, wo@16384, fw1@20480, fw2@28672 (36864 total)
__global__ __launch_bounds__(256) void k_pack(cfp wq, cfp wk, cfp wv, cfp getv, cfp wo,
                                              cfp fw1, cfp fw2, ushort* __restrict__ dst) {
  int layer = blockIdx.y;
  int e = blockIdx.x*256 + threadIdx.x;        // e < 36864
  const float* W; int N, rem;
  if (e < 20480) {
    int mm = e >> 12; rem = e & 4095;
    W = (mm==0?wq: mm==1?wk: mm==2?wv: mm==3?getv: wo) + layer*4096; N = 64;
  } else if (e < 28672) {
    rem = e - 20480; W = fw1 + layer*8192; N = 128;
  } else {
    rem = e - 28672; W = fw2 + layer*8192; N = 64;
  }
  int NT = N >> 4;
  int j = rem & 7, lane = (rem >> 3) & 63, rest = rem >> 9;
  int nt = rest % NT, ks = rest / NT;
  int k = ks*32 + ((lane >> 4) << 3) + j, n = nt*16 + (lane & 15);
  dst[(size_t)layer*36864 + e] = f2bf(W[(size_t)k*N + n]);
}

__global__ __launch_bounds__(256) void k_packe(cfp W, ushort* __restrict__ dst) {
  int e = blockIdx.x*256 + threadIdx.x;        // e < 4096
  int j = e & 7, lane = (e >> 3) & 63, rest = e >> 9;
  int nt = rest & 3, ks = rest >> 2;
  int k = ks*32 + ((lane >> 4) << 3) + j, n = nt*16 + (lane & 15);
  dst[e] = f2bf(W[k*64 + n]);
}

// ---------------- pooling (stem only) ----------------
__global__ __launch_bounds__(256) void k_pool_part(cfp h, fp pp) {
  int b = blockIdx.x, gblk = blockIdx.y, t = threadIdx.x;
  int c = t & 63, r = t >> 6;
  const float* base = h + ((size_t)b*LL + (size_t)gblk*256)*64;
  float acc = 0.f;
  for (int l = r; l < 256; l += 4) acc += base[(size_t)l*64 + c];
  __shared__ float red[4][64];
  red[r][c] = acc; __syncthreads();
  if (t < 64) pp[(b*16 + gblk)*64 + t] = red[0][t]+red[1][t]+red[2][t]+red[3][t];
}

__global__ void k_pool_fin(cfp pp, fp means, int chunks) {
  int b = blockIdx.x, c = threadIdx.x;
  float s = 0.f;
  for (int g = 0; g < chunks; ++g) s += pp[(b*chunks + g)*64 + c];
  means[b*64 + c] = s * (1.f/4096.f);
}

// ---------------- dynamic conv: attention + effective kernel (bf16 B-frags) ----------------
__global__ __launch_bounds__(256) void k_weff(cfp means, cfp w1, cfp b1, cfp w2, cfp b2,
                                              cfp kern, ushort* __restrict__ weffB) {
  int b = blockIdx.x, t = threadIdx.x;
  __shared__ float pooled[64], hdn[16], attn[3];
  if (t < 64) pooled[t] = means[b*64 + t];
  __syncthreads();
  if (t < 16) {
    float a = b1[t];
    for (int c = 0; c < 64; ++c) a += pooled[c]*w1[t*64 + c];
    hdn[t] = fmaxf(a, 0.f);
  }
  __syncthreads();
  if (t < 3) {
    float a = b2[t];
    for (int j = 0; j < 16; ++j) a += hdn[j]*w2[t*16 + j];
    attn[t] = a;
  }
  __syncthreads();
  if (t == 0) {
    float m = fmaxf(attn[0], fmaxf(attn[1], attn[2]));
    float e0 = __expf(attn[0]-m), e1 = __expf(attn[1]-m), e2 = __expf(attn[2]-m);
    float s = e0+e1+e2;
    attn[0]=e0/s; attn[1]=e1/s; attn[2]=e2/s;
  }
  __syncthreads();
  float a0=attn[0], a1=attn[1], a2=attn[2];
  for (int e = t; e < 12288; e += 256) {
    int j = e & 7, lane = (e >> 3) & 63, nt = (e >> 9) & 3, ks = e >> 11;
    int k = ks*32 + ((lane >> 4) << 3) + j;
    int co = nt*16 + (lane & 15);
    int kh = k >> 6, ci = k & 63;
    size_t base = ((size_t)co*64 + ci)*9 + kh*3 + 1;     // kw=1 only (W=1 with pad)
    float v = a0*kern[base] + a1*kern[base + 36864] + a2*kern[base + 2*36864];
    weffB[(size_t)b*12288 + e] = f2bf(v);
  }
}

// ---------------- 3-tap conv along L as K=192 MFMA GEMM ----------------
__global__ __launch_bounds__(256) void k_conv(cfp hin, const ushort* __restrict__ weffB,
                                              fp hout, fp pp) {
  int b = blockIdx.x, wblk = blockIdx.y, t = threadIdx.x;
  int n0 = wblk*64;
  __shared__ ushort Ts[66*72];          // rows n0-1..n0+64 bf16, stride 72
  __shared__ float red[64*17];
  for (int idx = t; idx < 1056; idx += 256) {
    int r = idx >> 4, c4 = (idx & 15)*4, gr = n0 - 1 + r;
    float4 v = make_float4(0.f,0.f,0.f,0.f);
    if (gr >= 0 && gr < LL) v = ld4(hin + ((size_t)b*LL + gr)*64 + c4);
    *(uint2*)(Ts + r*72 + c4) = pack4(v);
  }
  __syncthreads();
  int w = t >> 6, l = t & 63, band = w*16, lr = l & 15, lg = l >> 4;
  const ushort* wb = weffB + (size_t)b*12288;
  f32x4 acc[4];
  #pragma unroll
  for (int nt = 0; nt < 4; ++nt) acc[nt] = zf4();
  #pragma unroll
  for (int ks = 0; ks < 6; ++ks) {
    int k8 = ks*32 + lg*8;
    int kh = k8 >> 6, ci = k8 & 63;
    bf16x8 a = ldfrag(Ts + (band + lr + kh)*72 + ci);
    #pragma unroll
    for (int nt = 0; nt < 4; ++nt)
      acc[nt] = MFMA16(a, ldfrag(wb + ((ks*4+nt)*64 + l)*8), acc[nt]);
  }
  #pragma unroll
  for (int nt = 0; nt < 4; ++nt) {
    int co = nt*16 + lr;
    float part = 0.f;
    #pragma unroll
    for (int reg = 0; reg < 4; ++reg) {
      int row = band + lg*4 + reg;
      float v = acc[nt][reg];
      hout[((size_t)b*LL + n0 + row)*64 + co] = v;
      part += v;
    }
    red[co*17 + w*4 + lg] = part;
  }
  __syncthreads();
  if (t < 64) {
    float s = 0.f;
    #pragma unroll
    for (int g = 0; g < 16; ++g) s += red[t*17 + g];
    pp[((size_t)b*64 + wblk)*64 + t] = s;
  }
}

// ---------------- emb GEMM (MFMA) + pooling emission ----------------
__global__ __launch_bounds__(256) void k_emb(cfp X, const ushort* __restrict__ wE,
                                             cfp bias, fp Y, fp pp) {
  __shared__ ushort XB[64*72];
  __shared__ float red[64*17];
  int t = threadIdx.x; size_t n0 = (size_t)blockIdx.x*64;
  int w = t >> 6, l = t & 63, band = w*16, lr = l & 15, lg = l >> 4;
  #pragma unroll
  for (int it = 0; it < 4; ++it) {
    int idx = it*256 + t, r = idx >> 4, c4 = (idx & 15)*4;
    *(uint2*)(XB + r*72 + c4) = pack4(ld4(X + (n0 + r)*64 + c4));
  }
  __syncthreads();
  f32x4 acc[4];
  #pragma unroll
  for (int nt = 0; nt < 4; ++nt) acc[nt] = zf4();
  #pragma unroll
  for (int ks = 0; ks < 2; ++ks) {
    bf16x8 a = ldfrag(XB + (band + lr)*72 + ks*32 + lg*8);
    #pragma unroll
    for (int nt = 0; nt < 4; ++nt)
      acc[nt] = MFMA16(a, ldfrag(wE + ((ks*4+nt)*64 + l)*8), acc[nt]);
  }
  #pragma unroll
  for (int nt = 0; nt < 4; ++nt) {
    int col = nt*16 + lr;
    float bc = bias[col], part = 0.f;
    #pragma unroll
    for (int reg = 0; reg < 4; ++reg) {
      int row = band + lg*4 + reg;
      float y = acc[nt][reg] + bc;
      Y[(n0 + row)*64 + col] = y;
      part += y;
    }
    red[col*17 + w*4 + lg] = part;
  }
  __syncthreads();
  if (t < 64) {
    float s = 0.f;
    #pragma unroll
    for (int g = 0; g < 16; ++g) s += red[t*17 + g];
    pp[(size_t)blockIdx.x*64 + t] = s;
  }
}

// ---------------- agent attention: chunked scores + weighted-sum partials ----------------
__global__ __launch_bounds__(256) void k_agent2(cfp h, cfp anb, cfp pp,
                                                fp pm, fp pe, fp pw) {
  int b = blockIdx.x, ch = blockIdx.y, t = threadIdx.x;
  int w = t >> 6, l = t & 63;
  __shared__ float means_s[64];
  __shared__ float sc[8][258];
  __shared__ float red4[4][64];
  __shared__ float esp[8][33];
  __shared__ float mcs[8], ess[8];
  __shared__ float wred[4][8][64];
  {
    float acc = 0.f;
    for (int c = w; c < 64; c += 4) acc += pp[((size_t)b*64 + c)*64 + l];
    red4[w][l] = acc;
  }
  __syncthreads();
  if (t < 64) means_s[t] = (red4[0][t]+red4[1][t]+red4[2][t]+red4[3][t])
                           * (1.f/4096.f) * 0.35355339059327373f;
  __syncthreads();
  const float* hb = h + ((size_t)b*LL + (size_t)ch*256)*64;
  float ms = means_s[l];
  for (int i = 0; i < 64; ++i) {
    int n = w*64 + i;
    float v = hb[(size_t)n*64 + l] * ms;
    v += __shfl_xor(v, 1); v += __shfl_xor(v, 2); v += __shfl_xor(v, 4);
    if ((l & 7) == 0) sc[l >> 3][n] = v;
  }
  __syncthreads();
  int hh = t >> 5, j0 = (t & 31) * 8;
  const float* ab = anb + (size_t)hh*LL + ch*256 + j0;
  float loc[8];
  float mx = -1e30f;
  #pragma unroll
  for (int k = 0; k < 8; ++k) {
    loc[k] = sc[hh][j0 + k] + ab[k];
    mx = fmaxf(mx, loc[k]);
  }
  esp[hh][t & 31] = mx;
  __syncthreads();
  if (t < 8) {
    float m = -1e30f;
    for (int k = 0; k < 32; ++k) m = fmaxf(m, esp[t][k]);
    mcs[t] = m;
  }
  __syncthreads();
  {
    float M = mcs[hh], s = 0.f;
    #pragma unroll
    for (int k = 0; k < 8; ++k) {
      float e = __expf(loc[k] - M);
      sc[hh][j0 + k] = e;
      s += e;
    }
    esp[hh][t & 31] = s;
  }
  __syncthreads();
  if (t < 8) {
    float s = 0.f;
    for (int k = 0; k < 32; ++k) s += esp[t][k];
    ess[t] = s;
  }
  float acc8[8] = {};
  for (int i = 0; i < 64; ++i) {
    int n = w*64 + i;
    float x = hb[(size_t)n*64 + l];
    #pragma unroll
    for (int q = 0; q < 8; ++q) acc8[q] = fmaf(sc[q][n], x, acc8[q]);
  }
  __syncthreads();
  #pragma unroll
  for (int q = 0; q < 8; ++q) wred[w][q][l] = acc8[q];
  __syncthreads();
  for (int o = t; o < 512; o += 256) {
    int q = o >> 6, ll = o & 63;
    pw[(((size_t)b*16 + ch)*8 + q)*64 + ll] =
        wred[0][q][ll]+wred[1][q][ll]+wred[2][q][ll]+wred[3][q][ll];
  }
  if (t < 8) {
    pe[((size_t)b*16 + ch)*8 + t] = ess[t];
    pm[((size_t)b*16 + ch)*8 + t] = mcs[t];
  }
}

// ---------------- agent finalize: merge chunks (rescale) + getv projection ----------------
__global__ __launch_bounds__(256) void k_agfin(cfp pm, cfp pe, cfp pw,
                                               cfp getv, cfp getvb, fp agv) {
  int b = blockIdx.x, t = threadIdx.x;
  __shared__ float wm[8][65];
  __shared__ float Ms[8], den[8];
  if (t < 8) {
    float M = -1e30f;
    for (int c = 0; c < 16; ++c) M = fmaxf(M, pm[((size_t)b*16+c)*8 + t]);
    float d = 0.f;
    for (int c = 0; c < 16; ++c)
      d += pe[((size_t)b*16+c)*8 + t] * __expf(pm[((size_t)b*16+c)*8 + t] - M);
    Ms[t] = M; den[t] = d;
  }
  __syncthreads();
  for (int o = t; o < 512; o += 256) {
    int q = o >> 6, l = o & 63;
    float s = 0.f;
    for (int c = 0; c < 16; ++c)
      s += pw[(((size_t)b*16+c)*8 + q)*64 + l] * __expf(pm[((size_t)b*16+c)*8 + q] - Ms[q]);
    wm[q][l] = s / den[q];
  }
  __syncthreads();
  if (t < 64) {
    int q = t >> 3;
    float a = getvb[t];
    for (int c = 0; c < 64; ++c) a = fmaf(wm[q][c], getv[c*64 + t], a);
    agv[b*64 + t] = a;
  }
}

// ================= fused layer kernel (all-MFMA) =================
__global__ __launch_bounds__(256, 2) void k_layer(
    cfp h, cfp agvp, const ushort* __restrict__ wB,
    cfp bq, cfp bk, cfp bv, cfp getvb, cfp bo,
    cfp g1, cfp be1, cfp b1, cfp b2, cfp g2, cfp be2,
    fp Y, fp pp) {
  __shared__ float smem[14336];                  // 57344 B -> 2 blocks/CU
  float*  Hs   = smem;                           // [64][68] f32
  ushort* HsB  = (ushort*)(smem + 4352);         // [64][72] bf16
  ushort* Qp   = (ushort*)(smem + 6656);         // [4][64][20] bf16 (Q*0.25+bq)
  ushort* Kp   = (ushort*)(smem + 9216);         // [4][64][20] bf16
  ushort* Vt   = (ushort*)(smem + 11776);        // [4][16][72] bf16 (d-major)
  float*  sums = smem + 14080;                   // [4][64]
  ushort* OB   = (ushort*)(smem + 11776);        // [64][72]  (aliases Vt)
  float*  red  = smem + 11776;                   // [64][17]  (aliases Vt/OB)
  ushort* HidB = (ushort*)(smem + 6656);         // [64][136] (aliases Qp+Kp)

  int t = threadIdx.x;
  size_t n0 = (size_t)blockIdx.x*64;
  int b = (int)(n0 >> 12);
  int w = t >> 6, l = t & 63, band = w*16, lr = l & 15, lg = l >> 4;

  // stage h tile: fp32 + bf16
  #pragma unroll
  for (int it = 0; it < 4; ++it) {
    int idx = it*256 + t, r = idx >> 4, c4 = (idx & 15)*4;
    float4 v = ld4(h + (n0 + r)*64 + c4);
    st4(&Hs[r*68 + c4], v);
    *(uint2*)(HsB + r*72 + c4) = pack4(v);
  }
  __syncthreads();

  // ---- Q,K,V,lepe MFMA GEMMs ----
  f32x4 ka[4], va[4], qa[4], la[4];
  #pragma unroll
  for (int nt = 0; nt < 4; ++nt) {
    ka[nt] = zf4(); va[nt] = zf4(); qa[nt] = zf4(); la[nt] = zf4();
  }
  #pragma unroll
  for (int ks = 0; ks < 2; ++ks) {
    bf16x8 a = ldfrag(HsB + (band + lr)*72 + ks*32 + lg*8);
    #pragma unroll
    for (int nt = 0; nt < 4; ++nt) {
      int fo = ((ks*4 + nt)*64 + l)*8;
      qa[nt] = MFMA16(a, ldfrag(wB + fo),         qa[nt]);
      ka[nt] = MFMA16(a, ldfrag(wB + 4096 + fo),  ka[nt]);
      va[nt] = MFMA16(a, ldfrag(wB + 8192 + fo),  va[nt]);
      la[nt] = MFMA16(a, ldfrag(wB + 12288 + fo), la[nt]);
    }
  }
  #pragma unroll
  for (int nt = 0; nt < 4; ++nt) {
    int col = nt*16 + lr;
    float bkc = bk[col], bvc = bv[col], bqc = bq[col];
    #pragma unroll
    for (int reg = 0; reg < 4; ++reg) {
      int tok = band + 4*lg + reg;
      Kp[nt*1280 + tok*20 + lr] = f2bf(ka[nt][reg] + bkc);
      Qp[nt*1280 + tok*20 + lr] = f2bf((qa[nt][reg] + bqc) * 0.25f);
    }
    int tok0 = band + 4*lg;
    *(uint2*)(Vt + nt*1152 + lr*72 + tok0) =
        make_uint2(packf2(va[nt][0]+bvc, va[nt][1]+bvc),
                   packf2(va[nt][2]+bvc, va[nt][3]+bvc));
  }
  __syncthreads();

  // ---- windowed attention: wave = head; MFMA S^T = K*Q^T (slot-paired K_eff=16) ----
  {
    frag_u kaf[4], qbf[4], vbf[4], pf;
    #pragma unroll
    for (int tt = 0; tt < 4; ++tt) {
      kaf[tt].u2[0] = *(const uint2*)(Kp + w*1280 + (tt*16+lr)*20 + lg*4);
      kaf[tt].u[2] = 0; kaf[tt].u[3] = 0;
      qbf[tt].u2[0] = *(const uint2*)(Qp + w*1280 + (tt*16+lr)*20 + lg*4);
      qbf[tt].u[2] = 0; qbf[tt].u[3] = 0;
      vbf[tt].u2[0] = *(const uint2*)(Vt + w*1152 + lr*72 + tt*16 + lg*4);
      vbf[tt].u[2] = 0; vbf[tt].u[3] = 0;
    }
    f32x4 st[4][4];
    #pragma unroll
    for (int kt = 0; kt < 4; ++kt)
      #pragma unroll
      for (int qt = 0; qt < 4; ++qt) {
        f32x4 z = zf4();
        st[kt][qt] = MFMA16(kaf[kt].v, qbf[qt].v, z);
      }
    // lane (lr,lg) holds S^T[kt*16+4lg+reg][qt*16+lr]; softmax per q over (kt,reg,lg)
    f32x4 oacc[4];
    #pragma unroll
    for (int qt = 0; qt < 4; ++qt) {
      float M = -1e30f;
      #pragma unroll
      for (int kt = 0; kt < 4; ++kt)
        #pragma unroll
        for (int reg = 0; reg < 4; ++reg) M = fmaxf(M, st[kt][qt][reg]);
      M = fmaxf(M, __shfl_xor(M, 16));
      M = fmaxf(M, __shfl_xor(M, 32));
      float s = 0.f;
      #pragma unroll
      for (int kt = 0; kt < 4; ++kt)
        #pragma unroll
        for (int reg = 0; reg < 4; ++reg) {
          float e = __expf(st[kt][qt][reg] - M);
          st[kt][qt][reg] = e; s += e;
        }
      s += __shfl_xor(s, 16);
      s += __shfl_xor(s, 32);
      if (lg == 0) sums[w*64 + qt*16 + lr] = s;
      oacc[qt] = zf4();
    }
    // PV: P-fragments come straight from st (C-layout == A-frag layout)
    #pragma unroll
    for (int qt = 0; qt < 4; ++qt)
      #pragma unroll
      for (int kt = 0; kt < 4; ++kt) {
        pf.u[0] = packf2(st[kt][qt][0], st[kt][qt][1]);
        pf.u[1] = packf2(st[kt][qt][2], st[kt][qt][3]);
        pf.u[2] = 0; pf.u[3] = 0;
        oacc[qt] = MFMA16(pf.v, vbf[kt].v, oacc[qt]);
      }
    __syncthreads();      // all Qp/Kp/Vt reads done -> OB may overwrite Vt
    #pragma unroll
    for (int qt = 0; qt < 4; ++qt)
      #pragma unroll
      for (int reg = 0; reg < 4; ++reg) {
        int q = qt*16 + 4*lg + reg;
        OB[q*72 + band + lr] = f2bf(oacc[qt][reg] / sums[w*64 + q]);
      }
  }
  __syncthreads();

  // ---- O@Wo + bo + agent + residual(h) + lepe -> LN1 ----
  float comb[4][4];
  {
    f32x4 wa[4];
    #pragma unroll
    for (int nt = 0; nt < 4; ++nt) wa[nt] = zf4();
    #pragma unroll
    for (int ks = 0; ks < 2; ++ks) {
      bf16x8 a = ldfrag(OB + (band + lr)*72 + ks*32 + lg*8);
      #pragma unroll
      for (int nt = 0; nt < 4; ++nt)
        wa[nt] = MFMA16(a, ldfrag(wB + 16384 + ((ks*4+nt)*64 + l)*8), wa[nt]);
    }
    #pragma unroll
    for (int nt = 0; nt < 4; ++nt) {
      int col = nt*16 + lr;
      float cadd = bo[col] + agvp[b*64 + col] + getvb[col];
      #pragma unroll
      for (int reg = 0; reg < 4; ++reg) {
        int row = band + lg*4 + reg;
        comb[nt][reg] = wa[nt][reg] + la[nt][reg] + cadd + Hs[row*68 + col];
      }
    }
  }
  {
    float mean1[4], rstd1[4];
    #pragma unroll
    for (int reg = 0; reg < 4; ++reg) {
      float s = comb[0][reg]+comb[1][reg]+comb[2][reg]+comb[3][reg];
      float qq = comb[0][reg]*comb[0][reg]+comb[1][reg]*comb[1][reg]
               + comb[2][reg]*comb[2][reg]+comb[3][reg]*comb[3][reg];
      s += __shfl_xor(s,1); qq += __shfl_xor(qq,1);
      s += __shfl_xor(s,2); qq += __shfl_xor(qq,2);
      s += __shfl_xor(s,4); qq += __shfl_xor(qq,4);
      s += __shfl_xor(s,8); qq += __shfl_xor(qq,8);
      float mn = s*0.015625f;
      mean1[reg] = mn;
      rstd1[reg] = rsqrtf(qq*0.015625f - mn*mn + 1e-5f);
    }
    #pragma unroll
    for (int nt = 0; nt < 4; ++nt) {
      int col = nt*16 + lr;
      float gg = g1[col], bb = be1[col];
      #pragma unroll
      for (int reg = 0; reg < 4; ++reg) {
        int row = band + lg*4 + reg;
        float h1 = (comb[nt][reg]-mean1[reg])*rstd1[reg]*gg + bb;
        Hs[row*68 + col] = h1;
        HsB[row*72 + col] = f2bf(h1);
      }
    }
  }
  __syncthreads();

  // ---- FFN1: h1 @ W1 (64->128) + relu -> HidB ----
  {
    f32x4 fa[8];
    #pragma unroll
    for (int nt = 0; nt < 8; ++nt) fa[nt] = zf4();
    #pragma unroll
    for (int ks = 0; ks < 2; ++ks) {
      bf16x8 a = ldfrag(HsB + (band + lr)*72 + ks*32 + lg*8);
      #pragma unroll
      for (int nt = 0; nt < 8; ++nt)
        fa[nt] = MFMA16(a, ldfrag(wB + 20480 + ((ks*8+nt)*64 + l)*8), fa[nt]);
    }
    #pragma unroll
    for (int nt = 0; nt < 8; ++nt) {
      int col = nt*16 + lr;
      float b1c = b1[col];
      #pragma unroll
      for (int reg = 0; reg < 4; ++reg) {
        int row = band + lg*4 + reg;
        HidB[row*136 + col] = f2bf(fmaxf(fa[nt][reg] + b1c, 0.f));
      }
    }
  }
  __syncthreads();

  // ---- FFN2 + residual -> LN2 -> Y (+pool partials) ----
  {
    f32x4 f2[4];
    #pragma unroll
    for (int nt = 0; nt < 4; ++nt) f2[nt] = zf4();
    #pragma unroll
    for (int ks = 0; ks < 4; ++ks) {
      bf16x8 a = ldfrag(HidB + (band + lr)*136 + ks*32 + lg*8);
      #pragma unroll
      for (int nt = 0; nt < 4; ++nt)
        f2[nt] = MFMA16(a, ldfrag(wB + 28672 + ((ks*4+nt)*64 + l)*8), f2[nt]);
    }
    float c2[4][4];
    #pragma unroll
    for (int nt = 0; nt < 4; ++nt) {
      int col = nt*16 + lr;
      float b2c = b2[col];
      #pragma unroll
      for (int reg = 0; reg < 4; ++reg) {
        int row = band + lg*4 + reg;
        c2[nt][reg] = f2[nt][reg] + b2c + Hs[row*68 + col];
      }
    }
    float mean2[4], rstd2[4];
    #pragma unroll
    for (int reg = 0; reg < 4; ++reg) {
      float s = c2[0][reg]+c2[1][reg]+c2[2][reg]+c2[3][reg];
      float qq = c2[0][reg]*c2[0][reg]+c2[1][reg]*c2[1][reg]
               + c2[2][reg]*c2[2][reg]+c2[3][reg]*c2[3][reg];
      s += __shfl_xor(s,1); qq += __shfl_xor(qq,1);
      s += __shfl_xor(s,2); qq += __shfl_xor(qq,2);
      s += __shfl_xor(s,4); qq += __shfl_xor(qq,4);
      s += __shfl_xor(s,8); qq += __shfl_xor(qq,8);
      float mn = s*0.015625f;
      mean2[reg] = mn;
      rstd2[reg] = rsqrtf(qq*0.015625f - mn*mn + 1e-5f);
    }
    #pragma unroll
    for (int nt = 0; nt < 4; ++nt) {
      int col = nt*16 + lr;
      float gg = g2[col], bb = be2[col];
      float part = 0.f;
      #pragma unroll
      for (int reg = 0; reg < 4; ++reg) {
        int row = band + lg*4 + reg;
        float y = (c2[nt][reg]-mean2[reg])*rstd2[reg]*gg + bb;
        Y[(n0 + row)*64 + col] = y;
        part += y;
      }
      red[col*17 + w*4 + lg] = part;
    }
  }
  __syncthreads();
  if (t < 64) {
    float s = 0.f;
    #pragma unroll
    for (int g = 0; g < 16; ++g) s += red[t*17 + g];
    pp[(size_t)blockIdx.x*64 + t] = s;
  }
}

extern "C" void kernel_launch(void* const* d_in, const int* in_sizes, int n_in,
                              void* d_out, int out_size, void* d_ws, size_t ws_size,
                              hipStream_t stream) {
  (void)in_sizes; (void)n_in; (void)out_size; (void)ws_size;
  const float* x    = (const float*)d_in[0];
  const float* dck  = (const float*)d_in[1];
  const float* dcw1 = (const float*)d_in[2];
  const float* dcb1 = (const float*)d_in[3];
  const float* dcw2 = (const float*)d_in[4];
  const float* dcb2 = (const float*)d_in[5];
  const float* embw = (const float*)d_in[6];
  const float* embb = (const float*)d_in[7];
  const float* getvw= (const float*)d_in[8];
  const float* getvb= (const float*)d_in[9];
  const float* anb  = (const float*)d_in[10];
  // d_in[11] = na_bias: provably unused (softmax over size-1 axis == 1)
  const float* wq = (const float*)d_in[12]; const float* bq = (const float*)d_in[13];
  const float* wk = (const float*)d_in[14]; const float* bk = (const float*)d_in[15];
  const float* wv = (const float*)d_in[16]; const float* bv = (const float*)d_in[17];
  const float* wo = (const float*)d_in[18]; const float* bo = (const float*)d_in[19];
  const float* fw1= (const float*)d_in[20]; const float* fb1= (const float*)d_in[21];
  const float* fw2= (const float*)d_in[22]; const float* fb2= (const float*)d_in[23];
  const float* g1 = (const float*)d_in[24]; const float* be1= (const float*)d_in[25];
  const float* g2 = (const float*)d_in[26]; const float* be2= (const float*)d_in[27];

  float* out = (float*)d_out;
  float* ws  = (float*)d_ws;
  const size_t SZ = (size_t)BB*LL*DD;   // 4,194,304 floats
  float* bufA = ws;
  float* bufB = ws + SZ;
  float* pp    = ws + 2*SZ;                       // [16][64][64]
  float* means = pp + 65536;
  float* agv   = means + 1024;
  float* pm    = agv + 1024;                      // [16][16][8]
  float* pe    = pm + 2048;
  float* pw    = pe + 2048;                       // [16][16][8][64]
  ushort* weffB = (ushort*)(pw + 131072);         // 16 x 12288
  ushort* wsB   = weffB + (size_t)BB*12288;       // 3 x 36864
  ushort* wsE   = wsB + (size_t)3*36864;          // 4096

  dim3 blk(256);
  const int NT = BB*LL/64;  // 1024 row-tiles

  k_pack<<<dim3(144, 3), blk, 0, stream>>>(wq, wk, wv, getvw, wo, fw1, fw2, wsB);
  k_packe<<<16, blk, 0, stream>>>(embw, wsE);

  // ---- dynamic conv stem (3 stages) ----
  const float* cin = x;
  float* cout = bufA;
  for (int i = 0; i < 3; ++i) {
    if (i == 0) {
      k_pool_part<<<dim3(BB,16), blk, 0, stream>>>(x, pp);
      k_pool_fin<<<BB, 64, 0, stream>>>(pp, means, 16);
    } else {
      k_pool_fin<<<BB, 64, 0, stream>>>(pp, means, 64);
    }
    k_weff<<<BB, blk, 0, stream>>>(means, dcw1 + i*1024, dcb1 + i*16,
                                   dcw2 + i*48, dcb2 + i*3,
                                   dck + (size_t)i*110592, weffB);
    k_conv<<<dim3(BB,64), blk, 0, stream>>>(cin, weffB, cout, pp);
    cin = cout;
    cout = (cout == bufA) ? bufB : bufA;
  }
  // cin == bufA after 3 stages; embed into bufB (emits pooling partials for layer 1)
  k_emb<<<NT, blk, 0, stream>>>(cin, wsE, embb, bufB, pp);

  float* h  = bufB;
  float* hn = bufA;
  for (int i = 0; i < 3; ++i) {
    k_agent2<<<dim3(BB,16), blk, 0, stream>>>(h, anb + (size_t)i*8*4096, pp, pm, pe, pw);
    k_agfin<<<BB, blk, 0, stream>>>(pm, pe, pw, getvw + i*4096, getvb + i*64, agv);
    float* dst = (i == 2) ? out : hn;
    k_layer<<<NT, blk, 0, stream>>>(h, agv, wsB + (size_t)i*36864,
                                    bq + i*64, bk + i*64, bv + i*64, getvb + i*64, bo + i*64,
                                    g1 + i*64, be1 + i*64, fb1 + i*128, fb2 + i*64,
                                    g2 + i*64, be2 + i*64, dst, pp);
    float* tmp = h; h = hn; hn = tmp;
  }
}

// Round 6
// 302.539 us; speedup vs baseline: 3.0564x; 1.1115x over previous
//
#include <hip/hip_runtime.h>

#define BB 16
#define LL 4096
#define DD 64

typedef const float* __restrict__ cfp;
typedef float* __restrict__ fp;
typedef const ushort* __restrict__ cup;
typedef ushort* __restrict__ up;

typedef __attribute__((ext_vector_type(8))) short bf16x8;
typedef __attribute__((ext_vector_type(4))) float f32x4;
#define MFMA16(a, b, c) __builtin_amdgcn_mfma_f32_16x16x32_bf16(a, b, c, 0, 0, 0)

__device__ __forceinline__ f32x4 zf4(){ f32x4 z; z[0]=0.f; z[1]=0.f; z[2]=0.f; z[3]=0.f; return z; }

union frag_u { bf16x8 v; uint2 u2[2]; uint u[4]; };

__device__ __forceinline__ float4 ld4(const float* p){ return *reinterpret_cast<const float4*>(p); }
__device__ __forceinline__ void st4(float* p, float4 v){ *reinterpret_cast<float4*>(p) = v; }

__device__ __forceinline__ ushort f2bf(float f){
  uint u = __float_as_uint(f);
  return (ushort)((u + 0x7FFFu + ((u >> 16) & 1u)) >> 16);   // RNE
}
__device__ __forceinline__ float bf2f(ushort u){
  return __uint_as_float(((uint)u) << 16);
}
__device__ __forceinline__ uint packf2(float a, float b){
  return (uint)f2bf(a) | ((uint)f2bf(b) << 16);
}
__device__ __forceinline__ uint2 pack4(float4 v){
  return make_uint2(packf2(v.x, v.y), packf2(v.z, v.w));
}
__device__ __forceinline__ bf16x8 ldfrag(const ushort* p){ return *reinterpret_cast<const bf16x8*>(p); }

// ---------------- weight packing into bf16 B-fragments ----------------
// per layer: wq@0, wk@4096, wv@8192, getv@12288, wo@16384, fw1@20480, fw2@28672 (36864 total)
__global__ __launch_bounds__(256) void k_pack(cfp wq, cfp wk, cfp wv, cfp getv, cfp wo,
                                              cfp fw1, cfp fw2, up dst) {
  int layer = blockIdx.y;
  int e = blockIdx.x*256 + threadIdx.x;        // e < 36864
  const float* W; int N, rem;
  if (e < 20480) {
    int mm = e >> 12; rem = e & 4095;
    W = (mm==0?wq: mm==1?wk: mm==2?wv: mm==3?getv: wo) + layer*4096; N = 64;
  } else if (e < 28672) {
    rem = e - 20480; W = fw1 + layer*8192; N = 128;
  } else {
    rem = e - 28672; W = fw2 + layer*8192; N = 64;
  }
  int NT = N >> 4;
  int j = rem & 7, lane = (rem >> 3) & 63, rest = rem >> 9;
  int nt = rest % NT, ks = rest / NT;
  int k = ks*32 + ((lane >> 4) << 3) + j, n = nt*16 + (lane & 15);
  dst[(size_t)layer*36864 + e] = f2bf(W[(size_t)k*N + n]);
}

__global__ __launch_bounds__(256) void k_packe(cfp W, up dst) {
  int e = blockIdx.x*256 + threadIdx.x;        // e < 4096
  int j = e & 7, lane = (e >> 3) & 63, rest = e >> 9;
  int nt = rest & 3, ks = rest >> 2;
  int k = ks*32 + ((lane >> 4) << 3) + j, n = nt*16 + (lane & 15);
  dst[e] = f2bf(W[k*64 + n]);
}

// ---------------- pooling of raw input x (16 chunks) ----------------
__global__ __launch_bounds__(256) void k_pool_part(cfp h, fp pp) {
  int b = blockIdx.x, gblk = blockIdx.y, t = threadIdx.x;
  int c = t & 63, r = t >> 6;
  const float* base = h + ((size_t)b*LL + (size_t)gblk*256)*64;
  float acc = 0.f;
  for (int l = r; l < 256; l += 4) acc += base[(size_t)l*64 + c];
  __shared__ float red[4][64];
  red[r][c] = acc; __syncthreads();
  if (t < 64) pp[(b*16 + gblk)*64 + t] = red[0][t]+red[1][t]+red[2][t]+red[3][t];
}

// ---------------- dynamic conv: pool-finalize + attention + effective kernel ----------------
__global__ __launch_bounds__(256) void k_weff(cfp pp, int chunks,
                                              cfp w1, cfp b1, cfp w2, cfp b2,
                                              cfp kern, up weffB) {
  int b = blockIdx.x, t = threadIdx.x;
  __shared__ float pooled[64], hdn[16], attn[3];
  if (t < 64) {
    float s = 0.f;
    for (int g = 0; g < chunks; ++g) s += pp[((size_t)b*chunks + g)*64 + t];
    pooled[t] = s * (1.f/4096.f);
  }
  __syncthreads();
  if (t < 16) {
    float a = b1[t];
    for (int c = 0; c < 64; ++c) a += pooled[c]*w1[t*64 + c];
    hdn[t] = fmaxf(a, 0.f);
  }
  __syncthreads();
  if (t < 3) {
    float a = b2[t];
    for (int j = 0; j < 16; ++j) a += hdn[j]*w2[t*16 + j];
    attn[t] = a;
  }
  __syncthreads();
  if (t == 0) {
    float m = fmaxf(attn[0], fmaxf(attn[1], attn[2]));
    float e0 = __expf(attn[0]-m), e1 = __expf(attn[1]-m), e2 = __expf(attn[2]-m);
    float s = e0+e1+e2;
    attn[0]=e0/s; attn[1]=e1/s; attn[2]=e2/s;
  }
  __syncthreads();
  float a0=attn[0], a1=attn[1], a2=attn[2];
  for (int e = t; e < 12288; e += 256) {
    int j = e & 7, lane = (e >> 3) & 63, nt = (e >> 9) & 3, ks = e >> 11;
    int k = ks*32 + ((lane >> 4) << 3) + j;
    int co = nt*16 + (lane & 15);
    int kh = k >> 6, ci = k & 63;
    size_t base = ((size_t)co*64 + ci)*9 + kh*3 + 1;     // kw=1 only (W=1 with pad)
    float v = a0*kern[base] + a1*kern[base + 36864] + a2*kern[base + 2*36864];
    weffB[(size_t)b*12288 + e] = f2bf(v);
  }
}

// ---------------- conv MFMA core (Ts must be staged, sync'd) ----------------
__device__ __forceinline__ void conv_mfma(const ushort* Ts, const ushort* wb,
                                          int band, int lr, int lg, int l, f32x4 acc[4]) {
  #pragma unroll
  for (int nt = 0; nt < 4; ++nt) acc[nt] = zf4();
  #pragma unroll
  for (int ks = 0; ks < 6; ++ks) {
    int k8 = ks*32 + lg*8;
    int kh = k8 >> 6, ci = k8 & 63;
    bf16x8 a = ldfrag(Ts + (band + lr + kh)*72 + ci);
    #pragma unroll
    for (int nt = 0; nt < 4; ++nt)
      acc[nt] = MFMA16(a, ldfrag(wb + ((ks*4+nt)*64 + l)*8), acc[nt]);
  }
}

// ---------------- conv stage 0: fp32 in -> bf16 out + pool partials ----------------
__global__ __launch_bounds__(256) void k_conv0(cfp hin, cup weffB, up houtB, fp pp) {
  int b = blockIdx.x, wblk = blockIdx.y, t = threadIdx.x;
  int n0 = wblk*64;
  __shared__ ushort Ts[66*72];
  __shared__ float red[64*17];
  for (int idx = t; idx < 1056; idx += 256) {
    int r = idx >> 4, c4 = (idx & 15)*4, gr = n0 - 1 + r;
    float4 v = make_float4(0.f,0.f,0.f,0.f);
    if (gr >= 0 && gr < LL) v = ld4(hin + ((size_t)b*LL + gr)*64 + c4);
    *(uint2*)(Ts + r*72 + c4) = pack4(v);
  }
  __syncthreads();
  int w = t >> 6, l = t & 63, band = w*16, lr = l & 15, lg = l >> 4;
  f32x4 acc[4];
  conv_mfma(Ts, weffB + (size_t)b*12288, band, lr, lg, l, acc);
  __syncthreads();                       // Ts reads done
  #pragma unroll
  for (int nt = 0; nt < 4; ++nt) {
    int co = nt*16 + lr;
    float part = 0.f;
    #pragma unroll
    for (int reg = 0; reg < 4; ++reg) {
      int row = band + lg*4 + reg;
      Ts[row*72 + co] = f2bf(acc[nt][reg]);   // bounce C tile (rows 0..63)
      part += acc[nt][reg];
    }
    red[co*17 + w*4 + lg] = part;
  }
  __syncthreads();
  for (int idx = t; idx < 512; idx += 256) {
    int r = idx >> 3, c8 = (idx & 7)*8;
    *(uint4*)(houtB + ((size_t)b*LL + n0 + r)*64 + c8) = *(const uint4*)(Ts + r*72 + c8);
  }
  if (t < 64) {
    float s = 0.f;
    #pragma unroll
    for (int g = 0; g < 16; ++g) s += red[t*17 + g];
    pp[((size_t)b*64 + wblk)*64 + t] = s;
  }
}

// ---------------- conv stage 1: bf16 in -> bf16 out + pool partials ----------------
__global__ __launch_bounds__(256) void k_conv1(cup hinB, cup weffB, up houtB, fp pp) {
  int b = blockIdx.x, wblk = blockIdx.y, t = threadIdx.x;
  int n0 = wblk*64;
  __shared__ ushort Ts[66*72];
  __shared__ float red[64*17];
  for (int idx = t; idx < 528; idx += 256) {
    int r = idx >> 3, c8 = (idx & 7)*8, gr = n0 - 1 + r;
    uint4 v = make_uint4(0u,0u,0u,0u);
    if (gr >= 0 && gr < LL) v = *(const uint4*)(hinB + ((size_t)b*LL + gr)*64 + c8);
    *(uint4*)(Ts + r*72 + c8) = v;
  }
  __syncthreads();
  int w = t >> 6, l = t & 63, band = w*16, lr = l & 15, lg = l >> 4;
  f32x4 acc[4];
  conv_mfma(Ts, weffB + (size_t)b*12288, band, lr, lg, l, acc);
  __syncthreads();
  #pragma unroll
  for (int nt = 0; nt < 4; ++nt) {
    int co = nt*16 + lr;
    float part = 0.f;
    #pragma unroll
    for (int reg = 0; reg < 4; ++reg) {
      int row = band + lg*4 + reg;
      Ts[row*72 + co] = f2bf(acc[nt][reg]);
      part += acc[nt][reg];
    }
    red[co*17 + w*4 + lg] = part;
  }
  __syncthreads();
  for (int idx = t; idx < 512; idx += 256) {
    int r = idx >> 3, c8 = (idx & 7)*8;
    *(uint4*)(houtB + ((size_t)b*LL + n0 + r)*64 + c8) = *(const uint4*)(Ts + r*72 + c8);
  }
  if (t < 64) {
    float s = 0.f;
    #pragma unroll
    for (int g = 0; g < 16; ++g) s += red[t*17 + g];
    pp[((size_t)b*64 + wblk)*64 + t] = s;
  }
}

// ---------------- conv stage 2 + fused emb GEMM: bf16 in -> fp32 h + pool partials ----------------
__global__ __launch_bounds__(256) void k_conv2e(cup hinB, cup weffB, cup wE, cfp embb,
                                                fp Y, fp pp) {
  int b = blockIdx.x, wblk = blockIdx.y, t = threadIdx.x;
  int n0 = wblk*64;
  __shared__ ushort Ts[66*72];
  __shared__ float red[64*17];
  for (int idx = t; idx < 528; idx += 256) {
    int r = idx >> 3, c8 = (idx & 7)*8, gr = n0 - 1 + r;
    uint4 v = make_uint4(0u,0u,0u,0u);
    if (gr >= 0 && gr < LL) v = *(const uint4*)(hinB + ((size_t)b*LL + gr)*64 + c8);
    *(uint4*)(Ts + r*72 + c8) = v;
  }
  __syncthreads();
  int w = t >> 6, l = t & 63, band = w*16, lr = l & 15, lg = l >> 4;
  f32x4 acc[4];
  conv_mfma(Ts, weffB + (size_t)b*12288, band, lr, lg, l, acc);
  __syncthreads();
  #pragma unroll
  for (int nt = 0; nt < 4; ++nt) {
    int co = nt*16 + lr;
    #pragma unroll
    for (int reg = 0; reg < 4; ++reg)
      Ts[(band + lg*4 + reg)*72 + co] = f2bf(acc[nt][reg]);
  }
  __syncthreads();
  // emb GEMM: A = conv out rows, B = wE fragments
  f32x4 ea[4];
  #pragma unroll
  for (int nt = 0; nt < 4; ++nt) ea[nt] = zf4();
  #pragma unroll
  for (int ks = 0; ks < 2; ++ks) {
    bf16x8 a = ldfrag(Ts + (band + lr)*72 + ks*32 + lg*8);
    #pragma unroll
    for (int nt = 0; nt < 4; ++nt)
      ea[nt] = MFMA16(a, ldfrag(wE + ((ks*4+nt)*64 + l)*8), ea[nt]);
  }
  #pragma unroll
  for (int nt = 0; nt < 4; ++nt) {
    int col = nt*16 + lr;
    float bc = embb[col], part = 0.f;
    #pragma unroll
    for (int reg = 0; reg < 4; ++reg) {
      int row = band + lg*4 + reg;
      float y = ea[nt][reg] + bc;
      Y[((size_t)b*LL + n0 + row)*64 + col] = y;
      part += y;
    }
    red[col*17 + w*4 + lg] = part;
  }
  __syncthreads();
  if (t < 64) {
    float s = 0.f;
    #pragma unroll
    for (int g = 0; g < 16; ++g) s += red[t*17 + g];
    pp[((size_t)b*64 + wblk)*64 + t] = s;
  }
}

// ---------------- agent attention: chunked scores + weighted-sum partials ----------------
__global__ __launch_bounds__(256) void k_agent2(cfp h, cfp anb, cfp pp,
                                                fp pm, fp pe, fp pw) {
  int b = blockIdx.x, ch = blockIdx.y, t = threadIdx.x;
  int w = t >> 6, l = t & 63;
  __shared__ float means_s[64];
  __shared__ float sc[8][258];
  __shared__ float red4[4][64];
  __shared__ float esp[8][33];
  __shared__ float mcs[8], ess[8];
  __shared__ float wred[4][8][64];
  {
    float acc = 0.f;
    for (int c = w; c < 64; c += 4) acc += pp[((size_t)b*64 + c)*64 + l];
    red4[w][l] = acc;
  }
  __syncthreads();
  if (t < 64) means_s[t] = (red4[0][t]+red4[1][t]+red4[2][t]+red4[3][t])
                           * (1.f/4096.f) * 0.35355339059327373f;
  __syncthreads();
  const float* hb = h + ((size_t)b*LL + (size_t)ch*256)*64;
  float ms = means_s[l];
  for (int i = 0; i < 64; ++i) {
    int n = w*64 + i;
    float v = hb[(size_t)n*64 + l] * ms;
    v += __shfl_xor(v, 1); v += __shfl_xor(v, 2); v += __shfl_xor(v, 4);
    if ((l & 7) == 0) sc[l >> 3][n] = v;
  }
  __syncthreads();
  int hh = t >> 5, j0 = (t & 31) * 8;
  const float* ab = anb + (size_t)hh*LL + ch*256 + j0;
  float loc[8];
  float mx = -1e30f;
  #pragma unroll
  for (int k = 0; k < 8; ++k) {
    loc[k] = sc[hh][j0 + k] + ab[k];
    mx = fmaxf(mx, loc[k]);
  }
  esp[hh][t & 31] = mx;
  __syncthreads();
  if (t < 8) {
    float m = -1e30f;
    for (int k = 0; k < 32; ++k) m = fmaxf(m, esp[t][k]);
    mcs[t] = m;
  }
  __syncthreads();
  {
    float M = mcs[hh], s = 0.f;
    #pragma unroll
    for (int k = 0; k < 8; ++k) {
      float e = __expf(loc[k] - M);
      sc[hh][j0 + k] = e;
      s += e;
    }
    esp[hh][t & 31] = s;
  }
  __syncthreads();
  if (t < 8) {
    float s = 0.f;
    for (int k = 0; k < 32; ++k) s += esp[t][k];
    ess[t] = s;
  }
  float acc8[8] = {};
  for (int i = 0; i < 64; ++i) {
    int n = w*64 + i;
    float x = hb[(size_t)n*64 + l];
    #pragma unroll
    for (int q = 0; q < 8; ++q) acc8[q] = fmaf(sc[q][n], x, acc8[q]);
  }
  __syncthreads();
  #pragma unroll
  for (int q = 0; q < 8; ++q) wred[w][q][l] = acc8[q];
  __syncthreads();
  for (int o = t; o < 512; o += 256) {
    int q = o >> 6, ll = o & 63;
    pw[(((size_t)b*16 + ch)*8 + q)*64 + ll] =
        wred[0][q][ll]+wred[1][q][ll]+wred[2][q][ll]+wred[3][q][ll];
  }
  if (t < 8) {
    pe[((size_t)b*16 + ch)*8 + t] = ess[t];
    pm[((size_t)b*16 + ch)*8 + t] = mcs[t];
  }
}

// ================= fused layer kernel (all-MFMA, agfin folded, bf16 residual) =================
// LDS (floats): HsB@0 (2304) | Qp@2304 (2560) | Kp@4864 (2560) | Vt@7424 (2304) |
//   sums@9728 (256) | agvs@9984 (64)  => 10048 fl = 40192 B -> 4 blocks/CU
// aliases on Vt: wm/msden (prologue), OB, red. HidB aliases Qp+Kp.
__global__ __launch_bounds__(256, 4) void k_layer(
    cfp h, cfp pm, cfp pe, cfp pw, cfp getv, cfp getvb, cup wB,
    cfp bq, cfp bk, cfp bv, cfp bo,
    cfp g1, cfp be1, cfp b1, cfp b2, cfp g2, cfp be2,
    fp Y, fp pp) {
  __shared__ float smem[10048];
  ushort* HsB  = (ushort*)(smem);
  ushort* Qp   = (ushort*)(smem + 2304);
  ushort* Kp   = (ushort*)(smem + 4864);
  ushort* Vt   = (ushort*)(smem + 7424);
  float*  sums = smem + 9728;
  float*  agvs = smem + 9984;
  float*  wm   = smem + 7424;          // [8][65] alias Vt (prologue only)
  float*  msden= smem + 7944;          // 16 fl
  ushort* OB   = (ushort*)(smem + 7424);
  float*  red  = smem + 7424;
  ushort* HidB = (ushort*)(smem + 2304);

  int t = threadIdx.x;
  size_t n0 = (size_t)blockIdx.x*64;
  int b = (int)(n0 >> 12);
  int w = t >> 6, l = t & 63, band = w*16, lr = l & 15, lg = l >> 4;

  // stage h tile (bf16 only)
  #pragma unroll
  for (int it = 0; it < 4; ++it) {
    int idx = it*256 + t, r = idx >> 4, c4 = (idx & 15)*4;
    *(uint2*)(HsB + r*72 + c4) = pack4(ld4(h + (n0 + r)*64 + c4));
  }
  // ---- agent finalize (redundant per block; pm/pe/pw are L2-hot) ----
  if (t < 8) {
    float M = -1e30f;
    for (int c = 0; c < 16; ++c) M = fmaxf(M, pm[((size_t)b*16+c)*8 + t]);
    float d = 0.f;
    for (int c = 0; c < 16; ++c)
      d += pe[((size_t)b*16+c)*8 + t] * __expf(pm[((size_t)b*16+c)*8 + t] - M);
    msden[t] = M; msden[8+t] = d;
  }
  __syncthreads();
  for (int o = t; o < 512; o += 256) {
    int q = o >> 6, l2 = o & 63;
    float M = msden[q], s = 0.f;
    for (int c = 0; c < 16; ++c)
      s += pw[(((size_t)b*16+c)*8 + q)*64 + l2] * __expf(pm[((size_t)b*16+c)*8 + q] - M);
    wm[q*65 + l2] = s / msden[8+q];
  }
  __syncthreads();
  if (t < 64) {
    int q = t >> 3;
    float a = getvb[t];
    for (int c = 0; c < 64; ++c) a = fmaf(wm[q*65 + c], getv[c*64 + t], a);
    agvs[t] = a;
  }
  __syncthreads();

  // ---- Q,K,V,lepe MFMA GEMMs ----
  f32x4 ka[4], va[4], qa[4], la[4];
  #pragma unroll
  for (int nt = 0; nt < 4; ++nt) {
    ka[nt] = zf4(); va[nt] = zf4(); qa[nt] = zf4(); la[nt] = zf4();
  }
  #pragma unroll
  for (int ks = 0; ks < 2; ++ks) {
    bf16x8 a = ldfrag(HsB + (band + lr)*72 + ks*32 + lg*8);
    #pragma unroll
    for (int nt = 0; nt < 4; ++nt) {
      int fo = ((ks*4 + nt)*64 + l)*8;
      qa[nt] = MFMA16(a, ldfrag(wB + fo),         qa[nt]);
      ka[nt] = MFMA16(a, ldfrag(wB + 4096 + fo),  ka[nt]);
      va[nt] = MFMA16(a, ldfrag(wB + 8192 + fo),  va[nt]);
      la[nt] = MFMA16(a, ldfrag(wB + 12288 + fo), la[nt]);
    }
  }
  #pragma unroll
  for (int nt = 0; nt < 4; ++nt) {
    int col = nt*16 + lr;
    float bkc = bk[col], bvc = bv[col], bqc = bq[col];
    #pragma unroll
    for (int reg = 0; reg < 4; ++reg) {
      int tok = band + 4*lg + reg;
      Kp[nt*1280 + tok*20 + lr] = f2bf(ka[nt][reg] + bkc);
      Qp[nt*1280 + tok*20 + lr] = f2bf((qa[nt][reg] + bqc) * 0.25f);
    }
    int tok0 = band + 4*lg;
    *(uint2*)(Vt + nt*1152 + lr*72 + tok0) =
        make_uint2(packf2(va[nt][0]+bvc, va[nt][1]+bvc),
                   packf2(va[nt][2]+bvc, va[nt][3]+bvc));
  }
  __syncthreads();

  // ---- windowed attention: wave = head; MFMA S^T = K*Q^T (slot-paired K_eff=16) ----
  {
    frag_u kaf[4], qbf[4], vbf[4], pf;
    #pragma unroll
    for (int tt = 0; tt < 4; ++tt) {
      kaf[tt].u2[0] = *(const uint2*)(Kp + w*1280 + (tt*16+lr)*20 + lg*4);
      kaf[tt].u[2] = 0; kaf[tt].u[3] = 0;
      qbf[tt].u2[0] = *(const uint2*)(Qp + w*1280 + (tt*16+lr)*20 + lg*4);
      qbf[tt].u[2] = 0; qbf[tt].u[3] = 0;
      vbf[tt].u2[0] = *(const uint2*)(Vt + w*1152 + lr*72 + tt*16 + lg*4);
      vbf[tt].u[2] = 0; vbf[tt].u[3] = 0;
    }
    f32x4 st[4][4];
    #pragma unroll
    for (int kt = 0; kt < 4; ++kt)
      #pragma unroll
      for (int qt = 0; qt < 4; ++qt) {
        f32x4 z = zf4();
        st[kt][qt] = MFMA16(kaf[kt].v, qbf[qt].v, z);
      }
    f32x4 oacc[4];
    #pragma unroll
    for (int qt = 0; qt < 4; ++qt) {
      float M = -1e30f;
      #pragma unroll
      for (int kt = 0; kt < 4; ++kt)
        #pragma unroll
        for (int reg = 0; reg < 4; ++reg) M = fmaxf(M, st[kt][qt][reg]);
      M = fmaxf(M, __shfl_xor(M, 16));
      M = fmaxf(M, __shfl_xor(M, 32));
      float s = 0.f;
      #pragma unroll
      for (int kt = 0; kt < 4; ++kt)
        #pragma unroll
        for (int reg = 0; reg < 4; ++reg) {
          float e = __expf(st[kt][qt][reg] - M);
          st[kt][qt][reg] = e; s += e;
        }
      s += __shfl_xor(s, 16);
      s += __shfl_xor(s, 32);
      if (lg == 0) sums[w*64 + qt*16 + lr] = s;
      oacc[qt] = zf4();
    }
    #pragma unroll
    for (int qt = 0; qt < 4; ++qt)
      #pragma unroll
      for (int kt = 0; kt < 4; ++kt) {
        pf.u[0] = packf2(st[kt][qt][0], st[kt][qt][1]);
        pf.u[1] = packf2(st[kt][qt][2], st[kt][qt][3]);
        pf.u[2] = 0; pf.u[3] = 0;
        oacc[qt] = MFMA16(pf.v, vbf[kt].v, oacc[qt]);
      }
    __syncthreads();      // all Qp/Kp/Vt reads done -> OB may overwrite Vt
    #pragma unroll
    for (int qt = 0; qt < 4; ++qt)
      #pragma unroll
      for (int reg = 0; reg < 4; ++reg) {
        int q = qt*16 + 4*lg + reg;
        OB[q*72 + band + lr] = f2bf(oacc[qt][reg] / sums[w*64 + q]);
      }
  }
  __syncthreads();

  // ---- O@Wo + bo + agent + residual(h bf16) + lepe -> LN1 ----
  float comb[4][4];
  {
    f32x4 wa[4];
    #pragma unroll
    for (int nt = 0; nt < 4; ++nt) wa[nt] = zf4();
    #pragma unroll
    for (int ks = 0; ks < 2; ++ks) {
      bf16x8 a = ldfrag(OB + (band + lr)*72 + ks*32 + lg*8);
      #pragma unroll
      for (int nt = 0; nt < 4; ++nt)
        wa[nt] = MFMA16(a, ldfrag(wB + 16384 + ((ks*4+nt)*64 + l)*8), wa[nt]);
    }
    #pragma unroll
    for (int nt = 0; nt < 4; ++nt) {
      int col = nt*16 + lr;
      float cadd = bo[col] + agvs[col] + getvb[col];
      #pragma unroll
      for (int reg = 0; reg < 4; ++reg) {
        int row = band + lg*4 + reg;
        comb[nt][reg] = wa[nt][reg] + la[nt][reg] + cadd + bf2f(HsB[row*72 + col]);
      }
    }
  }
  {
    float mean1[4], rstd1[4];
    #pragma unroll
    for (int reg = 0; reg < 4; ++reg) {
      float s = comb[0][reg]+comb[1][reg]+comb[2][reg]+comb[3][reg];
      float qq = comb[0][reg]*comb[0][reg]+comb[1][reg]*comb[1][reg]
               + comb[2][reg]*comb[2][reg]+comb[3][reg]*comb[3][reg];
      s += __shfl_xor(s,1); qq += __shfl_xor(qq,1);
      s += __shfl_xor(s,2); qq += __shfl_xor(qq,2);
      s += __shfl_xor(s,4); qq += __shfl_xor(qq,4);
      s += __shfl_xor(s,8); qq += __shfl_xor(qq,8);
      float mn = s*0.015625f;
      mean1[reg] = mn;
      rstd1[reg] = rsqrtf(qq*0.015625f - mn*mn + 1e-5f);
    }
    #pragma unroll
    for (int nt = 0; nt < 4; ++nt) {
      int col = nt*16 + lr;
      float gg = g1[col], bb = be1[col];
      #pragma unroll
      for (int reg = 0; reg < 4; ++reg) {
        int row = band + lg*4 + reg;
        float h1 = (comb[nt][reg]-mean1[reg])*rstd1[reg]*gg + bb;
        HsB[row*72 + col] = f2bf(h1);     // own position: read above, write here, no race
      }
    }
  }
  __syncthreads();

  // ---- FFN1: h1 @ W1 (64->128) + relu -> HidB ----
  {
    f32x4 fa[8];
    #pragma unroll
    for (int nt = 0; nt < 8; ++nt) fa[nt] = zf4();
    #pragma unroll
    for (int ks = 0; ks < 2; ++ks) {
      bf16x8 a = ldfrag(HsB + (band + lr)*72 + ks*32 + lg*8);
      #pragma unroll
      for (int nt = 0; nt < 8; ++nt)
        fa[nt] = MFMA16(a, ldfrag(wB + 20480 + ((ks*8+nt)*64 + l)*8), fa[nt]);
    }
    #pragma unroll
    for (int nt = 0; nt < 8; ++nt) {
      int col = nt*16 + lr;
      float b1c = b1[col];
      #pragma unroll
      for (int reg = 0; reg < 4; ++reg) {
        int row = band + lg*4 + reg;
        HidB[row*136 + col] = f2bf(fmaxf(fa[nt][reg] + b1c, 0.f));
      }
    }
  }
  __syncthreads();

  // ---- FFN2 + residual(h1 bf16) -> LN2 -> Y (+pool partials) ----
  {
    f32x4 f2[4];
    #pragma unroll
    for (int nt = 0; nt < 4; ++nt) f2[nt] = zf4();
    #pragma unroll
    for (int ks = 0; ks < 4; ++ks) {
      bf16x8 a = ldfrag(HidB + (band + lr)*136 + ks*32 + lg*8);
      #pragma unroll
      for (int nt = 0; nt < 4; ++nt)
        f2[nt] = MFMA16(a, ldfrag(wB + 28672 + ((ks*4+nt)*64 + l)*8), f2[nt]);
    }
    float c2[4][4];
    #pragma unroll
    for (int nt = 0; nt < 4; ++nt) {
      int col = nt*16 + lr;
      float b2c = b2[col];
      #pragma unroll
      for (int reg = 0; reg < 4; ++reg) {
        int row = band + lg*4 + reg;
        c2[nt][reg] = f2[nt][reg] + b2c + bf2f(HsB[row*72 + col]);
      }
    }
    float mean2[4], rstd2[4];
    #pragma unroll
    for (int reg = 0; reg < 4; ++reg) {
      float s = c2[0][reg]+c2[1][reg]+c2[2][reg]+c2[3][reg];
      float qq = c2[0][reg]*c2[0][reg]+c2[1][reg]*c2[1][reg]
               + c2[2][reg]*c2[2][reg]+c2[3][reg]*c2[3][reg];
      s += __shfl_xor(s,1); qq += __shfl_xor(qq,1);
      s += __shfl_xor(s,2); qq += __shfl_xor(qq,2);
      s += __shfl_xor(s,4); qq += __shfl_xor(qq,4);
      s += __shfl_xor(s,8); qq += __shfl_xor(qq,8);
      float mn = s*0.015625f;
      mean2[reg] = mn;
      rstd2[reg] = rsqrtf(qq*0.015625f - mn*mn + 1e-5f);
    }
    __syncthreads();     // HidB reads done; red (alias Vt) free
    #pragma unroll
    for (int nt = 0; nt < 4; ++nt) {
      int col = nt*16 + lr;
      float gg = g2[col], bb = be2[col];
      float part = 0.f;
      #pragma unroll
      for (int reg = 0; reg < 4; ++reg) {
        int row = band + lg*4 + reg;
        float y = (c2[nt][reg]-mean2[reg])*rstd2[reg]*gg + bb;
        Y[(n0 + row)*64 + col] = y;
        part += y;
      }
      red[col*17 + w*4 + lg] = part;
    }
  }
  __syncthreads();
  if (t < 64) {
    float s = 0.f;
    #pragma unroll
    for (int g = 0; g < 16; ++g) s += red[t*17 + g];
    pp[(size_t)blockIdx.x*64 + t] = s;
  }
}

extern "C" void kernel_launch(void* const* d_in, const int* in_sizes, int n_in,
                              void* d_out, int out_size, void* d_ws, size_t ws_size,
                              hipStream_t stream) {
  (void)in_sizes; (void)n_in; (void)out_size; (void)ws_size;
  const float* x    = (const float*)d_in[0];
  const float* dck  = (const float*)d_in[1];
  const float* dcw1 = (const float*)d_in[2];
  const float* dcb1 = (const float*)d_in[3];
  const float* dcw2 = (const float*)d_in[4];
  const float* dcb2 = (const float*)d_in[5];
  const float* embw = (const float*)d_in[6];
  const float* embb = (const float*)d_in[7];
  const float* getvw= (const float*)d_in[8];
  const float* getvb= (const float*)d_in[9];
  const float* anb  = (const float*)d_in[10];
  // d_in[11] = na_bias: provably unused (softmax over size-1 axis == 1)
  const float* wq = (const float*)d_in[12]; const float* bq = (const float*)d_in[13];
  const float* wk = (const float*)d_in[14]; const float* bk = (const float*)d_in[15];
  const float* wv = (const float*)d_in[16]; const float* bv = (const float*)d_in[17];
  const float* wo = (const float*)d_in[18]; const float* bo = (const float*)d_in[19];
  const float* fw1= (const float*)d_in[20]; const float* fb1= (const float*)d_in[21];
  const float* fw2= (const float*)d_in[22]; const float* fb2= (const float*)d_in[23];
  const float* g1 = (const float*)d_in[24]; const float* be1= (const float*)d_in[25];
  const float* g2 = (const float*)d_in[26]; const float* be2= (const float*)d_in[27];

  float* out = (float*)d_out;
  float* ws  = (float*)d_ws;
  const size_t SZ = (size_t)BB*LL*DD;   // 4,194,304 floats
  float* bufC = ws;                     // h buffers (fp32)
  float* bufD = ws + SZ;
  float* pp   = ws + 2*SZ;              // [16][64][64]
  float* pm   = pp + 65536;             // [16][16][8]
  float* pe   = pm + 2048;
  float* pw   = pe + 2048;              // [16][16][8][64]
  ushort* hB0  = (ushort*)(pw + 131072);          // bf16 conv intermediates (8 MB each)
  ushort* hB1  = hB0 + (size_t)BB*LL*64;
  ushort* weffB= hB1 + (size_t)BB*LL*64;          // 16 x 12288
  ushort* wsB  = weffB + (size_t)BB*12288;        // 3 x 36864
  ushort* wsE  = wsB + (size_t)3*36864;           // 4096

  dim3 blk(256);
  const int NT = BB*LL/64;  // 1024 row-tiles

  k_pack<<<dim3(144, 3), blk, 0, stream>>>(wq, wk, wv, getvw, wo, fw1, fw2, wsB);
  k_packe<<<16, blk, 0, stream>>>(embw, wsE);

  // ---- dynamic conv stem (3 stages) + fused emb ----
  k_pool_part<<<dim3(BB,16), blk, 0, stream>>>(x, pp);
  k_weff<<<BB, blk, 0, stream>>>(pp, 16, dcw1, dcb1, dcw2, dcb2, dck, weffB);
  k_conv0<<<dim3(BB,64), blk, 0, stream>>>(x, weffB, hB0, pp);
  k_weff<<<BB, blk, 0, stream>>>(pp, 64, dcw1 + 1024, dcb1 + 16, dcw2 + 48, dcb2 + 3,
                                 dck + 110592, weffB);
  k_conv1<<<dim3(BB,64), blk, 0, stream>>>(hB0, weffB, hB1, pp);
  k_weff<<<BB, blk, 0, stream>>>(pp, 64, dcw1 + 2048, dcb1 + 32, dcw2 + 96, dcb2 + 6,
                                 dck + 221184, weffB);
  k_conv2e<<<dim3(BB,64), blk, 0, stream>>>(hB1, weffB, wsE, embb, bufC, pp);

  float* h  = bufC;
  float* hn = bufD;
  for (int i = 0; i < 3; ++i) {
    k_agent2<<<dim3(BB,16), blk, 0, stream>>>(h, anb + (size_t)i*8*4096, pp, pm, pe, pw);
    float* dst = (i == 2) ? out : hn;
    k_layer<<<NT, blk, 0, stream>>>(h, pm, pe, pw, getvw + i*4096, getvb + i*64,
                                    wsB + (size_t)i*36864,
                                    bq + i*64, bk + i*64, bv + i*64, bo + i*64,
                                    g1 + i*64, be1 + i*64, fb1 + i*128, fb2 + i*64,
                                    g2 + i*64, be2 + i*64, dst, pp);
    float* tmp = h; h = hn; hn = tmp;
  }
}

// Round 8
// 202.193 us; speedup vs baseline: 4.5732x; 1.4963x over previous
//
#include <hip/hip_runtime.h>

#define BB 16
#define LL 4096
#define DD 64

typedef const float* __restrict__ cfp;
typedef float* __restrict__ fp;
typedef const ushort* __restrict__ cup;
typedef ushort* __restrict__ up;

typedef __attribute__((ext_vector_type(8))) short bf16x8;
typedef __attribute__((ext_vector_type(4))) float f32x4;
#define MFMA16(a, b, c) __builtin_amdgcn_mfma_f32_16x16x32_bf16(a, b, c, 0, 0, 0)

__device__ __forceinline__ f32x4 zf4(){ f32x4 z; z[0]=0.f; z[1]=0.f; z[2]=0.f; z[3]=0.f; return z; }

union frag_u { bf16x8 v; uint2 u2[2]; uint u[4]; };

__device__ __forceinline__ float4 ld4(const float* p){ return *reinterpret_cast<const float4*>(p); }

__device__ __forceinline__ ushort f2bf(float f){
  uint u = __float_as_uint(f);
  return (ushort)((u + 0x7FFFu + ((u >> 16) & 1u)) >> 16);   // RNE
}
__device__ __forceinline__ float bf2f(ushort u){
  return __uint_as_float(((uint)u) << 16);
}
__device__ __forceinline__ uint packf2(float a, float b){
  return (uint)f2bf(a) | ((uint)f2bf(b) << 16);
}
__device__ __forceinline__ uint2 pack4(float4 v){
  return make_uint2(packf2(v.x, v.y), packf2(v.z, v.w));
}
__device__ __forceinline__ bf16x8 ldfrag(const ushort* p){ return *reinterpret_cast<const bf16x8*>(p); }

// ---------------- weight packing into bf16 B-fragments (+ emb) ----------------
// per layer: wq@0, wk@4096, wv@8192, getv@12288, wo@16384, fw1@20480, fw2@28672 (36864)
// e in [36864, 40960): emb pack (written redundantly by all 3 layer-rows)
__global__ __launch_bounds__(256) void k_pack(cfp wq, cfp wk, cfp wv, cfp getv, cfp wo,
                                              cfp fw1, cfp fw2, cfp embw,
                                              up dst, up dstE) {
  int layer = blockIdx.y;
  int e = blockIdx.x*256 + threadIdx.x;        // e < 40960
  if (e >= 36864) {
    int rem = e - 36864;
    int j = rem & 7, lane = (rem >> 3) & 63, rest = rem >> 9;
    int nt = rest & 3, ks = rest >> 2;
    int k = ks*32 + ((lane >> 4) << 3) + j, n = nt*16 + (lane & 15);
    dstE[rem] = f2bf(embw[k*64 + n]);
    return;
  }
  const float* W; int N, rem;
  if (e < 20480) {
    int mm = e >> 12; rem = e & 4095;
    W = (mm==0?wq: mm==1?wk: mm==2?wv: mm==3?getv: wo) + layer*4096; N = 64;
  } else if (e < 28672) {
    rem = e - 20480; W = fw1 + layer*8192; N = 128;
  } else {
    rem = e - 28672; W = fw2 + layer*8192; N = 64;
  }
  int NT = N >> 4;
  int j = rem & 7, lane = (rem >> 3) & 63, rest = rem >> 9;
  int nt = rest % NT, ks = rest / NT;
  int k = ks*32 + ((lane >> 4) << 3) + j, n = nt*16 + (lane & 15);
  dst[(size_t)layer*36864 + e] = f2bf(W[(size_t)k*N + n]);
}

// ---------------- pooling of raw input x (16 chunks) ----------------
__global__ __launch_bounds__(256) void k_pool_part(cfp h, fp pp) {
  int b = blockIdx.x, gblk = blockIdx.y, t = threadIdx.x;
  int c = t & 63, r = t >> 6;
  const float* base = h + ((size_t)b*LL + (size_t)gblk*256)*64;
  float acc = 0.f;
  for (int l = r; l < 256; l += 4) acc += base[(size_t)l*64 + c];
  __shared__ float red[4][64];
  red[r][c] = acc; __syncthreads();
  if (t < 64) pp[(b*16 + gblk)*64 + t] = red[0][t]+red[1][t]+red[2][t]+red[3][t];
}

// ---------------- dynamic conv: pool-finalize + attention + effective kernel ----------------
// grid (BB, 8): attn computed redundantly per block; each block writes a 1536-elem slice.
__global__ __launch_bounds__(256) void k_weff(cfp pp, int chunks,
                                              cfp w1, cfp b1, cfp w2, cfp b2,
                                              cfp kern, up weffB) {
  int b = blockIdx.x, t = threadIdx.x;
  __shared__ float pooled[64], hdn[16], attn[3];
  if (t < 64) {
    float s = 0.f;
    for (int g = 0; g < chunks; ++g) s += pp[((size_t)b*chunks + g)*64 + t];
    pooled[t] = s * (1.f/4096.f);
  }
  __syncthreads();
  if (t < 16) {
    float a = b1[t];
    for (int c = 0; c < 64; ++c) a += pooled[c]*w1[t*64 + c];
    hdn[t] = fmaxf(a, 0.f);
  }
  __syncthreads();
  if (t < 3) {
    float a = b2[t];
    for (int j = 0; j < 16; ++j) a += hdn[j]*w2[t*16 + j];
    attn[t] = a;
  }
  __syncthreads();
  if (t == 0) {
    float m = fmaxf(attn[0], fmaxf(attn[1], attn[2]));
    float e0 = __expf(attn[0]-m), e1 = __expf(attn[1]-m), e2 = __expf(attn[2]-m);
    float s = e0+e1+e2;
    attn[0]=e0/s; attn[1]=e1/s; attn[2]=e2/s;
  }
  __syncthreads();
  float a0=attn[0], a1=attn[1], a2=attn[2];
  int e0i = blockIdx.y * 1536;
  for (int e = e0i + t; e < e0i + 1536; e += 256) {
    int j = e & 7, lane = (e >> 3) & 63, nt = (e >> 9) & 3, ks = e >> 11;
    int k = ks*32 + ((lane >> 4) << 3) + j;
    int co = nt*16 + (lane & 15);
    int kh = k >> 6, ci = k & 63;
    size_t base = ((size_t)co*64 + ci)*9 + kh*3 + 1;     // kw=1 only (W=1 with pad)
    float v = a0*kern[base] + a1*kern[base + 36864] + a2*kern[base + 2*36864];
    weffB[(size_t)b*12288 + e] = f2bf(v);
  }
}

// ---------------- conv MFMA core (Ts must be staged, sync'd) ----------------
__device__ __forceinline__ void conv_mfma(const ushort* Ts, const ushort* wb,
                                          int band, int lr, int lg, int l, f32x4 acc[4]) {
  #pragma unroll
  for (int nt = 0; nt < 4; ++nt) acc[nt] = zf4();
  #pragma unroll
  for (int ks = 0; ks < 6; ++ks) {
    int k8 = ks*32 + lg*8;
    int kh = k8 >> 6, ci = k8 & 63;
    bf16x8 a = ldfrag(Ts + (band + lr + kh)*72 + ci);
    #pragma unroll
    for (int nt = 0; nt < 4; ++nt)
      acc[nt] = MFMA16(a, ldfrag(wb + ((ks*4+nt)*64 + l)*8), acc[nt]);
  }
}

// ---------------- conv stage 0: fp32 in -> bf16 out + pool partials ----------------
__global__ __launch_bounds__(256) void k_conv0(cfp hin, cup weffB, up houtB, fp pp) {
  int b = blockIdx.x, wblk = blockIdx.y, t = threadIdx.x;
  int n0 = wblk*64;
  __shared__ ushort Ts[66*72];
  __shared__ float red[64*17];
  for (int idx = t; idx < 1056; idx += 256) {
    int r = idx >> 4, c4 = (idx & 15)*4, gr = n0 - 1 + r;
    float4 v = make_float4(0.f,0.f,0.f,0.f);
    if (gr >= 0 && gr < LL) v = ld4(hin + ((size_t)b*LL + gr)*64 + c4);
    *(uint2*)(Ts + r*72 + c4) = pack4(v);
  }
  __syncthreads();
  int w = t >> 6, l = t & 63, band = w*16, lr = l & 15, lg = l >> 4;
  f32x4 acc[4];
  conv_mfma(Ts, weffB + (size_t)b*12288, band, lr, lg, l, acc);
  __syncthreads();                       // Ts reads done
  #pragma unroll
  for (int nt = 0; nt < 4; ++nt) {
    int co = nt*16 + lr;
    float part = 0.f;
    #pragma unroll
    for (int reg = 0; reg < 4; ++reg) {
      int row = band + lg*4 + reg;
      Ts[row*72 + co] = f2bf(acc[nt][reg]);   // bounce C tile (rows 0..63)
      part += acc[nt][reg];
    }
    red[co*17 + w*4 + lg] = part;
  }
  __syncthreads();
  for (int idx = t; idx < 512; idx += 256) {
    int r = idx >> 3, c8 = (idx & 7)*8;
    *(uint4*)(houtB + ((size_t)b*LL + n0 + r)*64 + c8) = *(const uint4*)(Ts + r*72 + c8);
  }
  if (t < 64) {
    float s = 0.f;
    #pragma unroll
    for (int g = 0; g < 16; ++g) s += red[t*17 + g];
    pp[((size_t)b*64 + wblk)*64 + t] = s;
  }
}

// ---------------- conv stage 1: bf16 in -> bf16 out + pool partials ----------------
__global__ __launch_bounds__(256) void k_conv1(cup hinB, cup weffB, up houtB, fp pp) {
  int b = blockIdx.x, wblk = blockIdx.y, t = threadIdx.x;
  int n0 = wblk*64;
  __shared__ ushort Ts[66*72];
  __shared__ float red[64*17];
  for (int idx = t; idx < 528; idx += 256) {
    int r = idx >> 3, c8 = (idx & 7)*8, gr = n0 - 1 + r;
    uint4 v = make_uint4(0u,0u,0u,0u);
    if (gr >= 0 && gr < LL) v = *(const uint4*)(hinB + ((size_t)b*LL + gr)*64 + c8);
    *(uint4*)(Ts + r*72 + c8) = v;
  }
  __syncthreads();
  int w = t >> 6, l = t & 63, band = w*16, lr = l & 15, lg = l >> 4;
  f32x4 acc[4];
  conv_mfma(Ts, weffB + (size_t)b*12288, band, lr, lg, l, acc);
  __syncthreads();
  #pragma unroll
  for (int nt = 0; nt < 4; ++nt) {
    int co = nt*16 + lr;
    float part = 0.f;
    #pragma unroll
    for (int reg = 0; reg < 4; ++reg) {
      int row = band + lg*4 + reg;
      Ts[row*72 + co] = f2bf(acc[nt][reg]);
      part += acc[nt][reg];
    }
    red[co*17 + w*4 + lg] = part;
  }
  __syncthreads();
  for (int idx = t; idx < 512; idx += 256) {
    int r = idx >> 3, c8 = (idx & 7)*8;
    *(uint4*)(houtB + ((size_t)b*LL + n0 + r)*64 + c8) = *(const uint4*)(Ts + r*72 + c8);
  }
  if (t < 64) {
    float s = 0.f;
    #pragma unroll
    for (int g = 0; g < 16; ++g) s += red[t*17 + g];
    pp[((size_t)b*64 + wblk)*64 + t] = s;
  }
}

// ---------------- conv stage 2 + fused emb GEMM: bf16 in -> bf16 h + pool partials ----------------
__global__ __launch_bounds__(256) void k_conv2e(cup hinB, cup weffB, cup wE, cfp embb,
                                                up houtB, fp pp) {
  int b = blockIdx.x, wblk = blockIdx.y, t = threadIdx.x;
  int n0 = wblk*64;
  __shared__ ushort Ts[66*72];
  __shared__ float red[64*17];
  for (int idx = t; idx < 528; idx += 256) {
    int r = idx >> 3, c8 = (idx & 7)*8, gr = n0 - 1 + r;
    uint4 v = make_uint4(0u,0u,0u,0u);
    if (gr >= 0 && gr < LL) v = *(const uint4*)(hinB + ((size_t)b*LL + gr)*64 + c8);
    *(uint4*)(Ts + r*72 + c8) = v;
  }
  __syncthreads();
  int w = t >> 6, l = t & 63, band = w*16, lr = l & 15, lg = l >> 4;
  f32x4 acc[4];
  conv_mfma(Ts, weffB + (size_t)b*12288, band, lr, lg, l, acc);
  __syncthreads();
  #pragma unroll
  for (int nt = 0; nt < 4; ++nt) {
    int co = nt*16 + lr;
    #pragma unroll
    for (int reg = 0; reg < 4; ++reg)
      Ts[(band + lg*4 + reg)*72 + co] = f2bf(acc[nt][reg]);
  }
  __syncthreads();
  // emb GEMM: A = conv out rows (own band only), B = wE fragments
  f32x4 ea[4];
  #pragma unroll
  for (int nt = 0; nt < 4; ++nt) ea[nt] = zf4();
  #pragma unroll
  for (int ks = 0; ks < 2; ++ks) {
    bf16x8 a = ldfrag(Ts + (band + lr)*72 + ks*32 + lg*8);
    #pragma unroll
    for (int nt = 0; nt < 4; ++nt)
      ea[nt] = MFMA16(a, ldfrag(wE + ((ks*4+nt)*64 + l)*8), ea[nt]);
  }
  #pragma unroll
  for (int nt = 0; nt < 4; ++nt) {
    int col = nt*16 + lr;
    float bc = embb[col], part = 0.f;
    #pragma unroll
    for (int reg = 0; reg < 4; ++reg) {
      int row = band + lg*4 + reg;
      float y = ea[nt][reg] + bc;
      Ts[row*72 + col] = f2bf(y);     // own band; in-wave read-before-write ordering holds
      part += y;
    }
    red[col*17 + w*4 + lg] = part;
  }
  __syncthreads();
  for (int idx = t; idx < 512; idx += 256) {
    int r = idx >> 3, c8 = (idx & 7)*8;
    *(uint4*)(houtB + ((size_t)b*LL + n0 + r)*64 + c8) = *(const uint4*)(Ts + r*72 + c8);
  }
  if (t < 64) {
    float s = 0.f;
    #pragma unroll
    for (int g = 0; g < 16; ++g) s += red[t*17 + g];
    pp[((size_t)b*64 + wblk)*64 + t] = s;
  }
}

// ---------------- agent attention: chunked scores + weighted-sum partials (bf16 h) ----------------
__global__ __launch_bounds__(256) void k_agent2(cup h16, cfp anb, cfp pp,
                                                fp pm, fp pe, fp pw) {
  int b = blockIdx.x, ch = blockIdx.y, t = threadIdx.x;
  int w = t >> 6, l = t & 63;
  __shared__ float means_s[64];
  __shared__ float sc[8][258];
  __shared__ float red4[4][64];
  __shared__ float esp[8][33];
  __shared__ float mcs[8], ess[8];
  __shared__ float wred[4][8][64];
  {
    float acc = 0.f;
    for (int c = w; c < 64; c += 4) acc += pp[((size_t)b*64 + c)*64 + l];
    red4[w][l] = acc;
  }
  __syncthreads();
  if (t < 64) means_s[t] = (red4[0][t]+red4[1][t]+red4[2][t]+red4[3][t])
                           * (1.f/4096.f) * 0.35355339059327373f;
  __syncthreads();
  const ushort* hb = h16 + ((size_t)b*LL + (size_t)ch*256)*64;
  // score phase: lane (g8=row-in-8, k8=head) computes head k8's 8-dim dot in-lane
  int g8 = l >> 3, k8 = l & 7;
  float ms8[8];
  #pragma unroll
  for (int j = 0; j < 8; ++j) ms8[j] = means_s[k8*8 + j];
  #pragma unroll
  for (int it = 0; it < 8; ++it) {
    int n = w*64 + it*8 + g8;
    uint4 hv = *(const uint4*)(hb + (size_t)n*64 + k8*8);
    float d = bf2f((ushort)(hv.x & 0xffffu))*ms8[0] + bf2f((ushort)(hv.x >> 16))*ms8[1]
            + bf2f((ushort)(hv.y & 0xffffu))*ms8[2] + bf2f((ushort)(hv.y >> 16))*ms8[3]
            + bf2f((ushort)(hv.z & 0xffffu))*ms8[4] + bf2f((ushort)(hv.z >> 16))*ms8[5]
            + bf2f((ushort)(hv.w & 0xffffu))*ms8[6] + bf2f((ushort)(hv.w >> 16))*ms8[7];
    sc[k8][n] = d;
  }
  __syncthreads();
  int hh = t >> 5, j0 = (t & 31) * 8;
  const float* ab = anb + (size_t)hh*LL + ch*256 + j0;
  float loc[8];
  float mx = -1e30f;
  #pragma unroll
  for (int k = 0; k < 8; ++k) {
    loc[k] = sc[hh][j0 + k] + ab[k];
    mx = fmaxf(mx, loc[k]);
  }
  esp[hh][t & 31] = mx;
  __syncthreads();
  if (t < 8) {
    float m = -1e30f;
    for (int k = 0; k < 32; ++k) m = fmaxf(m, esp[t][k]);
    mcs[t] = m;
  }
  __syncthreads();
  {
    float M = mcs[hh], s = 0.f;
    #pragma unroll
    for (int k = 0; k < 8; ++k) {
      float e = __expf(loc[k] - M);
      sc[hh][j0 + k] = e;
      s += e;
    }
    esp[hh][t & 31] = s;
  }
  __syncthreads();
  if (t < 8) {
    float s = 0.f;
    for (int k = 0; k < 32; ++k) s += esp[t][k];
    ess[t] = s;
  }
  float acc8[8] = {};
  for (int i = 0; i < 64; ++i) {
    int n = w*64 + i;
    float x = bf2f(hb[(size_t)n*64 + l]);
    #pragma unroll
    for (int q = 0; q < 8; ++q) acc8[q] = fmaf(sc[q][n], x, acc8[q]);
  }
  __syncthreads();
  #pragma unroll
  for (int q = 0; q < 8; ++q) wred[w][q][l] = acc8[q];
  __syncthreads();
  for (int o = t; o < 512; o += 256) {
    int q = o >> 6, ll = o & 63;
    pw[(((size_t)b*16 + ch)*8 + q)*64 + ll] =
        wred[0][q][ll]+wred[1][q][ll]+wred[2][q][ll]+wred[3][q][ll];
  }
  if (t < 8) {
    pe[((size_t)b*16 + ch)*8 + t] = ess[t];
    pm[((size_t)b*16 + ch)*8 + t] = mcs[t];
  }
}

// ================= fused layer kernel (all-MFMA, agfin folded, bf16 in; templated out) =================
template<bool OUT_BF16>
__global__ __launch_bounds__(256, 4) void k_layer(
    cup h16, cfp pm, cfp pe, cfp pw, cfp getv, cfp getvb, cup wB,
    cfp bq, cfp bk, cfp bv, cfp bo,
    cfp g1, cfp be1, cfp b1, cfp b2, cfp g2, cfp be2,
    fp Y, up Y16, fp pp) {
  __shared__ float smem[10048];
  ushort* HsB  = (ushort*)(smem);
  ushort* Qp   = (ushort*)(smem + 2304);
  ushort* Kp   = (ushort*)(smem + 4864);
  ushort* Vt   = (ushort*)(smem + 7424);
  float*  sums = smem + 9728;
  float*  agvs = smem + 9984;
  float*  wm   = smem + 7424;          // [8][65] alias Vt (prologue only)
  float*  msden= smem + 7944;          // 16 fl
  ushort* OB   = (ushort*)(smem + 7424);
  float*  red  = smem + 7424;
  ushort* HidB = (ushort*)(smem + 2304);

  int t = threadIdx.x;
  size_t n0 = (size_t)blockIdx.x*64;
  int b = (int)(n0 >> 12);
  int w = t >> 6, l = t & 63, band = w*16, lr = l & 15, lg = l >> 4;

  // stage h tile (bf16 direct copy)
  #pragma unroll
  for (int it = 0; it < 2; ++it) {
    int idx = it*256 + t, r = idx >> 3, c8 = (idx & 7)*8;
    *(uint4*)(HsB + r*72 + c8) = *(const uint4*)(h16 + (n0 + r)*64 + c8);
  }
  // ---- agent finalize (redundant per block; pm/pe/pw are L2-hot) ----
  if (t < 8) {
    float M = -1e30f;
    for (int c = 0; c < 16; ++c) M = fmaxf(M, pm[((size_t)b*16+c)*8 + t]);
    float d = 0.f;
    for (int c = 0; c < 16; ++c)
      d += pe[((size_t)b*16+c)*8 + t] * __expf(pm[((size_t)b*16+c)*8 + t] - M);
    msden[t] = M; msden[8+t] = d;
  }
  __syncthreads();
  for (int o = t; o < 512; o += 256) {
    int q = o >> 6, l2 = o & 63;
    float M = msden[q], s = 0.f;
    for (int c = 0; c < 16; ++c)
      s += pw[(((size_t)b*16+c)*8 + q)*64 + l2] * __expf(pm[((size_t)b*16+c)*8 + q] - M);
    wm[q*65 + l2] = s / msden[8+q];
  }
  __syncthreads();
  if (t < 64) {
    int q = t >> 3;
    float a = getvb[t];
    for (int c = 0; c < 64; ++c) a = fmaf(wm[q*65 + c], getv[c*64 + t], a);
    agvs[t] = a;
  }
  __syncthreads();

  // ---- Q,K,V,lepe MFMA GEMMs ----
  f32x4 ka[4], va[4], qa[4], la[4];
  #pragma unroll
  for (int nt = 0; nt < 4; ++nt) {
    ka[nt] = zf4(); va[nt] = zf4(); qa[nt] = zf4(); la[nt] = zf4();
  }
  #pragma unroll
  for (int ks = 0; ks < 2; ++ks) {
    bf16x8 a = ldfrag(HsB + (band + lr)*72 + ks*32 + lg*8);
    #pragma unroll
    for (int nt = 0; nt < 4; ++nt) {
      int fo = ((ks*4 + nt)*64 + l)*8;
      qa[nt] = MFMA16(a, ldfrag(wB + fo),         qa[nt]);
      ka[nt] = MFMA16(a, ldfrag(wB + 4096 + fo),  ka[nt]);
      va[nt] = MFMA16(a, ldfrag(wB + 8192 + fo),  va[nt]);
      la[nt] = MFMA16(a, ldfrag(wB + 12288 + fo), la[nt]);
    }
  }
  #pragma unroll
  for (int nt = 0; nt < 4; ++nt) {
    int col = nt*16 + lr;
    float bkc = bk[col], bvc = bv[col], bqc = bq[col];
    #pragma unroll
    for (int reg = 0; reg < 4; ++reg) {
      int tok = band + 4*lg + reg;
      Kp[nt*1280 + tok*20 + lr] = f2bf(ka[nt][reg] + bkc);
      Qp[nt*1280 + tok*20 + lr] = f2bf((qa[nt][reg] + bqc) * 0.25f);
    }
    int tok0 = band + 4*lg;
    *(uint2*)(Vt + nt*1152 + lr*72 + tok0) =
        make_uint2(packf2(va[nt][0]+bvc, va[nt][1]+bvc),
                   packf2(va[nt][2]+bvc, va[nt][3]+bvc));
  }
  __syncthreads();

  // ---- windowed attention: wave = head; MFMA S^T = K*Q^T (slot-paired K_eff=16) ----
  {
    frag_u kaf[4], qbf[4], vbf[4], pf;
    #pragma unroll
    for (int tt = 0; tt < 4; ++tt) {
      kaf[tt].u2[0] = *(const uint2*)(Kp + w*1280 + (tt*16+lr)*20 + lg*4);
      kaf[tt].u[2] = 0; kaf[tt].u[3] = 0;
      qbf[tt].u2[0] = *(const uint2*)(Qp + w*1280 + (tt*16+lr)*20 + lg*4);
      qbf[tt].u[2] = 0; qbf[tt].u[3] = 0;
      vbf[tt].u2[0] = *(const uint2*)(Vt + w*1152 + lr*72 + tt*16 + lg*4);
      vbf[tt].u[2] = 0; vbf[tt].u[3] = 0;
    }
    f32x4 st[4][4];
    #pragma unroll
    for (int kt = 0; kt < 4; ++kt)
      #pragma unroll
      for (int qt = 0; qt < 4; ++qt) {
        f32x4 z = zf4();
        st[kt][qt] = MFMA16(kaf[kt].v, qbf[qt].v, z);
      }
    f32x4 oacc[4];
    #pragma unroll
    for (int qt = 0; qt < 4; ++qt) {
      float M = -1e30f;
      #pragma unroll
      for (int kt = 0; kt < 4; ++kt)
        #pragma unroll
        for (int reg = 0; reg < 4; ++reg) M = fmaxf(M, st[kt][qt][reg]);
      M = fmaxf(M, __shfl_xor(M, 16));
      M = fmaxf(M, __shfl_xor(M, 32));
      float s = 0.f;
      #pragma unroll
      for (int kt = 0; kt < 4; ++kt)
        #pragma unroll
        for (int reg = 0; reg < 4; ++reg) {
          float e = __expf(st[kt][qt][reg] - M);
          st[kt][qt][reg] = e; s += e;
        }
      s += __shfl_xor(s, 16);
      s += __shfl_xor(s, 32);
      if (lg == 0) sums[w*64 + qt*16 + lr] = s;
      oacc[qt] = zf4();
    }
    #pragma unroll
    for (int qt = 0; qt < 4; ++qt)
      #pragma unroll
      for (int kt = 0; kt < 4; ++kt) {
        pf.u[0] = packf2(st[kt][qt][0], st[kt][qt][1]);
        pf.u[1] = packf2(st[kt][qt][2], st[kt][qt][3]);
        pf.u[2] = 0; pf.u[3] = 0;
        oacc[qt] = MFMA16(pf.v, vbf[kt].v, oacc[qt]);
      }
    __syncthreads();      // all Qp/Kp/Vt reads done -> OB may overwrite Vt
    #pragma unroll
    for (int qt = 0; qt < 4; ++qt)
      #pragma unroll
      for (int reg = 0; reg < 4; ++reg) {
        int q = qt*16 + 4*lg + reg;
        OB[q*72 + band + lr] = f2bf(oacc[qt][reg] / sums[w*64 + q]);
      }
  }
  __syncthreads();

  // ---- O@Wo + bo + agent + residual(h bf16) + lepe -> LN1 ----
  float comb[4][4];
  {
    f32x4 wa[4];
    #pragma unroll
    for (int nt = 0; nt < 4; ++nt) wa[nt] = zf4();
    #pragma unroll
    for (int ks = 0; ks < 2; ++ks) {
      bf16x8 a = ldfrag(OB + (band + lr)*72 + ks*32 + lg*8);
      #pragma unroll
      for (int nt = 0; nt < 4; ++nt)
        wa[nt] = MFMA16(a, ldfrag(wB + 16384 + ((ks*4+nt)*64 + l)*8), wa[nt]);
    }
    #pragma unroll
    for (int nt = 0; nt < 4; ++nt) {
      int col = nt*16 + lr;
      float cadd = bo[col] + agvs[col] + getvb[col];
      #pragma unroll
      for (int reg = 0; reg < 4; ++reg) {
        int row = band + lg*4 + reg;
        comb[nt][reg] = wa[nt][reg] + la[nt][reg] + cadd + bf2f(HsB[row*72 + col]);
      }
    }
  }
  {
    float mean1[4], rstd1[4];
    #pragma unroll
    for (int reg = 0; reg < 4; ++reg) {
      float s = comb[0][reg]+comb[1][reg]+comb[2][reg]+comb[3][reg];
      float qq = comb[0][reg]*comb[0][reg]+comb[1][reg]*comb[1][reg]
               + comb[2][reg]*comb[2][reg]+comb[3][reg]*comb[3][reg];
      s += __shfl_xor(s,1); qq += __shfl_xor(qq,1);
      s += __shfl_xor(s,2); qq += __shfl_xor(qq,2);
      s += __shfl_xor(s,4); qq += __shfl_xor(qq,4);
      s += __shfl_xor(s,8); qq += __shfl_xor(qq,8);
      float mn = s*0.015625f;
      mean1[reg] = mn;
      rstd1[reg] = rsqrtf(qq*0.015625f - mn*mn + 1e-5f);
    }
    #pragma unroll
    for (int nt = 0; nt < 4; ++nt) {
      int col = nt*16 + lr;
      float gg = g1[col], bb = be1[col];
      #pragma unroll
      for (int reg = 0; reg < 4; ++reg) {
        int row = band + lg*4 + reg;
        float h1 = (comb[nt][reg]-mean1[reg])*rstd1[reg]*gg + bb;
        HsB[row*72 + col] = f2bf(h1);     // own position: read above, write here, no race
      }
    }
  }
  __syncthreads();

  // ---- FFN1: h1 @ W1 (64->128) + relu -> HidB ----
  {
    f32x4 fa[8];
    #pragma unroll
    for (int nt = 0; nt < 8; ++nt) fa[nt] = zf4();
    #pragma unroll
    for (int ks = 0; ks < 2; ++ks) {
      bf16x8 a = ldfrag(HsB + (band + lr)*72 + ks*32 + lg*8);
      #pragma unroll
      for (int nt = 0; nt < 8; ++nt)
        fa[nt] = MFMA16(a, ldfrag(wB + 20480 + ((ks*8+nt)*64 + l)*8), fa[nt]);
    }
    #pragma unroll
    for (int nt = 0; nt < 8; ++nt) {
      int col = nt*16 + lr;
      float b1c = b1[col];
      #pragma unroll
      for (int reg = 0; reg < 4; ++reg) {
        int row = band + lg*4 + reg;
        HidB[row*136 + col] = f2bf(fmaxf(fa[nt][reg] + b1c, 0.f));
      }
    }
  }
  __syncthreads();

  // ---- FFN2 + residual(h1 bf16) -> LN2 -> out (+pool partials) ----
  {
    f32x4 f2[4];
    #pragma unroll
    for (int nt = 0; nt < 4; ++nt) f2[nt] = zf4();
    #pragma unroll
    for (int ks = 0; ks < 4; ++ks) {
      bf16x8 a = ldfrag(HidB + (band + lr)*136 + ks*32 + lg*8);
      #pragma unroll
      for (int nt = 0; nt < 4; ++nt)
        f2[nt] = MFMA16(a, ldfrag(wB + 28672 + ((ks*4+nt)*64 + l)*8), f2[nt]);
    }
    float c2[4][4];
    #pragma unroll
    for (int nt = 0; nt < 4; ++nt) {
      int col = nt*16 + lr;
      float b2c = b2[col];
      #pragma unroll
      for (int reg = 0; reg < 4; ++reg) {
        int row = band + lg*4 + reg;
        c2[nt][reg] = f2[nt][reg] + b2c + bf2f(HsB[row*72 + col]);
      }
    }
    float mean2[4], rstd2[4];
    #pragma unroll
    for (int reg = 0; reg < 4; ++reg) {
      float s = c2[0][reg]+c2[1][reg]+c2[2][reg]+c2[3][reg];
      float qq = c2[0][reg]*c2[0][reg]+c2[1][reg]*c2[1][reg]
               + c2[2][reg]*c2[2][reg]+c2[3][reg]*c2[3][reg];
      s += __shfl_xor(s,1); qq += __shfl_xor(qq,1);
      s += __shfl_xor(s,2); qq += __shfl_xor(qq,2);
      s += __shfl_xor(s,4); qq += __shfl_xor(qq,4);
      s += __shfl_xor(s,8); qq += __shfl_xor(qq,8);
      float mn = s*0.015625f;
      mean2[reg] = mn;
      rstd2[reg] = rsqrtf(qq*0.015625f - mn*mn + 1e-5f);
    }
    __syncthreads();     // HidB reads done; red (alias Vt) free
    #pragma unroll
    for (int nt = 0; nt < 4; ++nt) {
      int col = nt*16 + lr;
      float gg = g2[col], bb = be2[col];
      float part = 0.f;
      #pragma unroll
      for (int reg = 0; reg < 4; ++reg) {
        int row = band + lg*4 + reg;
        float y = (c2[nt][reg]-mean2[reg])*rstd2[reg]*gg + bb;
        if (OUT_BF16) Y16[(n0 + row)*64 + col] = f2bf(y);
        else          Y[(n0 + row)*64 + col] = y;
        part += y;
      }
      red[col*17 + w*4 + lg] = part;
    }
  }
  __syncthreads();
  if (t < 64) {
    float s = 0.f;
    #pragma unroll
    for (int g = 0; g < 16; ++g) s += red[t*17 + g];
    pp[(size_t)blockIdx.x*64 + t] = s;
  }
}

extern "C" void kernel_launch(void* const* d_in, const int* in_sizes, int n_in,
                              void* d_out, int out_size, void* d_ws, size_t ws_size,
                              hipStream_t stream) {
  (void)in_sizes; (void)n_in; (void)out_size; (void)ws_size;
  const float* x    = (const float*)d_in[0];
  const float* dck  = (const float*)d_in[1];
  const float* dcw1 = (const float*)d_in[2];
  const float* dcb1 = (const float*)d_in[3];
  const float* dcw2 = (const float*)d_in[4];
  const float* dcb2 = (const float*)d_in[5];
  const float* embw = (const float*)d_in[6];
  const float* embb = (const float*)d_in[7];
  const float* getvw= (const float*)d_in[8];
  const float* getvb= (const float*)d_in[9];
  const float* anb  = (const float*)d_in[10];
  // d_in[11] = na_bias: provably unused (softmax over size-1 axis == 1)
  const float* wq = (const float*)d_in[12]; const float* bq = (const float*)d_in[13];
  const float* wk = (const float*)d_in[14]; const float* bk = (const float*)d_in[15];
  const float* wv = (const float*)d_in[16]; const float* bv = (const float*)d_in[17];
  const float* wo = (const float*)d_in[18]; const float* bo = (const float*)d_in[19];
  const float* fw1= (const float*)d_in[20]; const float* fb1= (const float*)d_in[21];
  const float* fw2= (const float*)d_in[22]; const float* fb2= (const float*)d_in[23];
  const float* g1 = (const float*)d_in[24]; const float* be1= (const float*)d_in[25];
  const float* g2 = (const float*)d_in[26]; const float* be2= (const float*)d_in[27];

  float* out = (float*)d_out;
  float* ws  = (float*)d_ws;
  float* pp   = ws;                     // [16][64][64]
  float* pm   = pp + 65536;             // [16][16][8]
  float* pe   = pm + 2048;
  float* pw   = pe + 2048;              // [16][16][8][64]
  ushort* hB0  = (ushort*)(pw + 131072);          // bf16 h buffers (8.4 MB each)
  ushort* hB1  = hB0 + (size_t)BB*LL*64;
  ushort* weffB= hB1 + (size_t)BB*LL*64;          // 16 x 12288
  ushort* wsB  = weffB + (size_t)BB*12288;        // 3 x 36864
  ushort* wsE  = wsB + (size_t)3*36864;           // 4096

  dim3 blk(256);
  const int NT = BB*LL/64;  // 1024 row-tiles

  k_pack<<<dim3(160, 3), blk, 0, stream>>>(wq, wk, wv, getvw, wo, fw1, fw2, embw, wsB, wsE);

  // ---- dynamic conv stem (3 stages) + fused emb, bf16 intermediates ----
  k_pool_part<<<dim3(BB,16), blk, 0, stream>>>(x, pp);
  k_weff<<<dim3(BB,8), blk, 0, stream>>>(pp, 16, dcw1, dcb1, dcw2, dcb2, dck, weffB);
  k_conv0<<<dim3(BB,64), blk, 0, stream>>>(x, weffB, hB0, pp);
  k_weff<<<dim3(BB,8), blk, 0, stream>>>(pp, 64, dcw1 + 1024, dcb1 + 16, dcw2 + 48, dcb2 + 3,
                                         dck + 110592, weffB);
  k_conv1<<<dim3(BB,64), blk, 0, stream>>>(hB0, weffB, hB1, pp);
  k_weff<<<dim3(BB,8), blk, 0, stream>>>(pp, 64, dcw1 + 2048, dcb1 + 32, dcw2 + 96, dcb2 + 6,
                                         dck + 221184, weffB);
  k_conv2e<<<dim3(BB,64), blk, 0, stream>>>(hB1, weffB, wsE, embb, hB0, pp);

  ushort* h  = hB0;
  ushort* hn = hB1;
  for (int i = 0; i < 3; ++i) {
    k_agent2<<<dim3(BB,16), blk, 0, stream>>>(h, anb + (size_t)i*8*4096, pp, pm, pe, pw);
    if (i == 2) {
      k_layer<false><<<NT, blk, 0, stream>>>(h, pm, pe, pw, getvw + i*4096, getvb + i*64,
                                             wsB + (size_t)i*36864,
                                             bq + i*64, bk + i*64, bv + i*64, bo + i*64,
                                             g1 + i*64, be1 + i*64, fb1 + i*128, fb2 + i*64,
                                             g2 + i*64, be2 + i*64, out, nullptr, pp);
    } else {
      k_layer<true><<<NT, blk, 0, stream>>>(h, pm, pe, pw, getvw + i*4096, getvb + i*64,
                                            wsB + (size_t)i*36864,
                                            bq + i*64, bk + i*64, bv + i*64, bo + i*64,
                                            g1 + i*64, be1 + i*64, fb1 + i*128, fb2 + i*64,
                                            g2 + i*64, be2 + i*64, nullptr, hn, pp);
    }
    ushort* tmp = h; h = hn; hn = tmp;
  }
}